// Round 11
// baseline (14042.049 us; speedup 1.0000x reference)
//
#include <hip/hip_runtime.h>
#include <stdint.h>
#include <math.h>

// Problem constants (fixed by setup_inputs)
#define B_     128
#define S_     128
#define V_     8000
#define E_     512
#define H_     2048
#define H4_    8192
#define GIVEN_ 64

typedef __bf16 bf16x8 __attribute__((ext_vector_type(8)));
typedef float  f32x16 __attribute__((ext_vector_type(16)));
typedef short  short8 __attribute__((ext_vector_type(8)));

// ---------------------------------------------------------------------------
// Threefry-2x32 (20 rounds) — exact JAX semantics (verified passing r3-r7,r10)
// ---------------------------------------------------------------------------
__device__ __forceinline__ uint32_t rotl32(uint32_t v, int d) {
  return (v << d) | (v >> (32 - d));
}

__device__ __forceinline__ void threefry2x32(uint32_t k0, uint32_t k1,
                                             uint32_t x0, uint32_t x1,
                                             uint32_t& o0, uint32_t& o1) {
  uint32_t k2 = k0 ^ k1 ^ 0x1BD11BDAu;
  x0 += k0; x1 += k1;
#define TF_RND(R) { x0 += x1; x1 = rotl32(x1, (R)); x1 ^= x0; }
  TF_RND(13) TF_RND(15) TF_RND(26) TF_RND(6)
  x0 += k1; x1 += k2 + 1u;
  TF_RND(17) TF_RND(29) TF_RND(16) TF_RND(24)
  x0 += k2; x1 += k0 + 2u;
  TF_RND(13) TF_RND(15) TF_RND(26) TF_RND(6)
  x0 += k0; x1 += k1 + 3u;
  TF_RND(17) TF_RND(29) TF_RND(16) TF_RND(24)
  x0 += k1; x1 += k2 + 4u;
  TF_RND(13) TF_RND(15) TF_RND(26) TF_RND(6)
  x0 += k2; x1 += k0 + 5u;
#undef TF_RND
  o0 = x0; o1 = x1;
}

__global__ void keys_kernel(uint32_t* __restrict__ keys) {
  int t = threadIdx.x;  // 0..63
  uint32_t o0, o1;
  threefry2x32(0u, 1u, 0u, (uint32_t)t, o0, o1);
  keys[2 * t]     = o0;
  keys[2 * t + 1] = o1;
}

__global__ void copy_prefix(const int* __restrict__ x, int* __restrict__ out) {
  int idx = blockIdx.x * blockDim.x + threadIdx.x;
  int b = idx >> 6;
  int s = idx & 63;
  out[b * S_ + s] = x[b * S_ + s];
}

// split f32 -> hi/lo bf16 (truncation; identical math to passing rounds)
__device__ __forceinline__ void split2(float x, uint16_t& hi, uint16_t& lo) {
  uint32_t xb = __float_as_uint(x);
  hi = (uint16_t)(xb >> 16);
  float l = x - __uint_as_float(xb & 0xFFFF0000u);
  lo = (uint16_t)(__float_as_uint(l) >> 16);
}

__device__ __forceinline__ void splitpack(float4 a, float4 b,
                                          bf16x8& hi, bf16x8& lo) {
  float e[8] = {a.x, a.y, a.z, a.w, b.x, b.y, b.z, b.w};
  short8 h, l;
#pragma unroll
  for (int j = 0; j < 8; ++j) {
    uint16_t h16, l16;
    split2(e[j], h16, l16);
    h[j] = (short)h16;
    l[j] = (short)l16;
  }
  hi = __builtin_bit_cast(bf16x8, h);
  lo = __builtin_bit_cast(bf16x8, l);
}

// unpack packed-3B weight frag: hi bf16x8 (direct) + 8 mid-bytes -> lo bf16x8
__device__ __forceinline__ void unpack3(short8 hv, uint2 m, bf16x8& bh, bf16x8& bl) {
  short8 lv;
#pragma unroll
  for (int j = 0; j < 8; ++j) {
    uint32_t hbits = ((uint32_t)(uint16_t)hv[j]) << 16;
    uint32_t mbyte = ((j < 4 ? (m.x >> (8 * j)) : (m.y >> (8 * (j - 4)))) & 0xFFu);
    float xf = __uint_as_float(hbits | (mbyte << 8));
    float lf = xf - __uint_as_float(hbits);
    lv[j] = (short)(__float_as_uint(lf) >> 16);
  }
  bh = __builtin_bit_cast(bf16x8, hv);
  bl = __builtin_bit_cast(bf16x8, lv);
}

// pack f32 weights -> PH (top 16 bits) + PM (mantissa bits 8..16)
__global__ __launch_bounds__(256) void pack3(
    const float* __restrict__ W, uint16_t* __restrict__ PH,
    uint8_t* __restrict__ PM, int n8)
{
  int i = blockIdx.x * 256 + threadIdx.x;   // handles 8 elems
  if (i >= n8) return;
  float4 a = ((const float4*)W)[2 * i];
  float4 b = ((const float4*)W)[2 * i + 1];
  float e[8] = {a.x, a.y, a.z, a.w, b.x, b.y, b.z, b.w};
  short8 h;
  uint32_t mlo = 0, mhi = 0;
#pragma unroll
  for (int j = 0; j < 8; ++j) {
    uint32_t xb = __float_as_uint(e[j]);
    h[j] = (short)(xb >> 16);
    uint32_t mb = (xb >> 8) & 0xFFu;
    if (j < 4) mlo |= mb << (8 * j);
    else       mhi |= mb << (8 * (j - 4));
  }
  *(short8*)&PH[(size_t)i * 8] = h;
  *(uint2*)&PM[(size_t)i * 8] = make_uint2(mlo, mhi);
}

#define MFMA_(a, b, c) __builtin_amdgcn_mfma_f32_32x32x16_bf16(a, b, c, 0, 0, 0)

// ===========================================================================
// PACKED-B GEMM phase, 64x64 tile: acc[2][2] += A(64 x K) @ W^T (block's 64
// cols). B from PH/PM 3-byte panels, 4-deep prefetch; A (gathered-f32 emb or
// pre-split staged-h) 2-deep. 8 waves K-split: wave w takes steps w, w+8, ...
// staged-h layout: elem(b,n) at ((n>>4)*4+(b>>5))*512+((n>>3)&1)*256+(b&31)*8+(n&7)
// ===========================================================================
template<bool GATHER>
__device__ __forceinline__ void run_phase64_p(
    f32x16 (&acc)[2][2],
    const float* __restrict__ aF,
    const uint16_t* __restrict__ aHi, const uint16_t* __restrict__ aLo,
    int tok0, int tok1,
    const uint16_t* __restrict__ PH, const uint8_t* __restrict__ PM,
    int K, bool gateRe, int jb, int mb, int w, int lrow, int lgrp)
{
  const int nFS = K >> 7;          // 4 or 16 (multiple of 4)
  const int c0 = lrow, c1 = 32 + lrow;
  const int wrow0 = gateRe ? ((c0 >> 4) * H_ + jb * 16 + (c0 & 15)) : (jb * 64 + c0);
  const int wrow1 = gateRe ? ((c1 >> 4) * H_ + jb * 16 + (c1 & 15)) : (jb * 64 + c1);
  const size_t bb0 = (size_t)wrow0 * K + lgrp * 8;
  const size_t bb1 = (size_t)wrow1 * K + lgrp * 8;

  size_t aoff0, aoff1;
  if (GATHER) {
    aoff0 = (size_t)tok0 * E_ + lgrp * 8;
    aoff1 = (size_t)tok1 * E_ + lgrp * 8;
  } else {
    aoff0 = (size_t)(mb * 2) * 512 + (size_t)lgrp * 256 + (size_t)lrow * 8;
    aoff1 = aoff0 + 512;
  }

  // 4-deep B buffers, 2-deep A buffers (all statically indexed)
  short8 bH0[4], bH1[4]; uint2 bM0[4], bM1[4];
  float4 gA0[2][2], gA1[2][2];
  bf16x8 sh0[2], sh1[2], sl0[2], sl1[2];

#define BLOAD(BUF, KS)                                                       \
  {                                                                          \
    const size_t o0 = bb0 + (size_t)(KS) * 16;                               \
    const size_t o1 = bb1 + (size_t)(KS) * 16;                               \
    bH0[BUF] = *(const short8*)(PH + o0);                                    \
    bM0[BUF] = *(const uint2*)(PM + o0);                                     \
    bH1[BUF] = *(const short8*)(PH + o1);                                    \
    bM1[BUF] = *(const uint2*)(PM + o1);                                     \
  }

#define ALOAD(BUF, KS)                                                       \
  {                                                                          \
    if (GATHER) {                                                            \
      const float* a0 = aF + aoff0 + (size_t)(KS) * 16;                      \
      const float* a1 = aF + aoff1 + (size_t)(KS) * 16;                      \
      gA0[BUF][0] = ((const float4*)a0)[0];                                  \
      gA0[BUF][1] = ((const float4*)a0)[1];                                  \
      gA1[BUF][0] = ((const float4*)a1)[0];                                  \
      gA1[BUF][1] = ((const float4*)a1)[1];                                  \
    } else {                                                                 \
      size_t o0 = aoff0 + (size_t)(KS) * 2048;                               \
      size_t o1 = aoff1 + (size_t)(KS) * 2048;                               \
      sh0[BUF] = *(const bf16x8*)(aHi + o0);                                 \
      sl0[BUF] = *(const bf16x8*)(aLo + o0);                                 \
      sh1[BUF] = *(const bf16x8*)(aHi + o1);                                 \
      sl1[BUF] = *(const bf16x8*)(aLo + o1);                                 \
    }                                                                        \
  }

#define COMP(BB, AB)                                                         \
  {                                                                          \
    bf16x8 bh0, bl0, bh1, bl1;                                               \
    unpack3(bH0[BB], bM0[BB], bh0, bl0);                                     \
    unpack3(bH1[BB], bM1[BB], bh1, bl1);                                     \
    bf16x8 ah0, al0, ah1, al1;                                               \
    if (GATHER) {                                                            \
      splitpack(gA0[AB][0], gA0[AB][1], ah0, al0);                           \
      splitpack(gA1[AB][0], gA1[AB][1], ah1, al1);                           \
    } else {                                                                 \
      ah0 = sh0[AB]; al0 = sl0[AB];                                          \
      ah1 = sh1[AB]; al1 = sl1[AB];                                          \
    }                                                                        \
    acc[0][0] = MFMA_(ah0, bh0, acc[0][0]);                                  \
    acc[0][0] = MFMA_(ah0, bl0, acc[0][0]);                                  \
    acc[0][0] = MFMA_(al0, bh0, acc[0][0]);                                  \
    acc[0][1] = MFMA_(ah0, bh1, acc[0][1]);                                  \
    acc[0][1] = MFMA_(ah0, bl1, acc[0][1]);                                  \
    acc[0][1] = MFMA_(al0, bh1, acc[0][1]);                                  \
    acc[1][0] = MFMA_(ah1, bh0, acc[1][0]);                                  \
    acc[1][0] = MFMA_(ah1, bl0, acc[1][0]);                                  \
    acc[1][0] = MFMA_(al1, bh0, acc[1][0]);                                  \
    acc[1][1] = MFMA_(ah1, bh1, acc[1][1]);                                  \
    acc[1][1] = MFMA_(ah1, bl1, acc[1][1]);                                  \
    acc[1][1] = MFMA_(al1, bh1, acc[1][1]);                                  \
  }

  // prologue: B steps 0-3, A steps 0-1 (nFS >= 4 always)
  BLOAD(0, w); BLOAD(1, w + 8); BLOAD(2, w + 16); BLOAD(3, w + 24);
  ALOAD(0, w); ALOAD(1, w + 8);
  for (int it = 0; it < nFS; it += 4) {
    const int kb = w + it * 8;
    COMP(0, 0);
    if (it + 4 < nFS) BLOAD(0, kb + 32);
    if (it + 2 < nFS) ALOAD(0, kb + 16);
    COMP(1, 1);
    if (it + 5 < nFS) BLOAD(1, kb + 40);
    if (it + 3 < nFS) ALOAD(1, kb + 24);
    COMP(2, 0);
    if (it + 6 < nFS) BLOAD(2, kb + 48);
    if (it + 4 < nFS) ALOAD(0, kb + 32);
    COMP(3, 1);
    if (it + 7 < nFS) BLOAD(3, kb + 56);
    if (it + 5 < nFS) ALOAD(1, kb + 40);
  }
#undef BLOAD
#undef ALOAD
#undef COMP
}

// ---------------------------------------------------------------------------
// Fused dual-GEMM + epilogue, tile M=64 (mb=blockIdx.y) x N=64 (jb=blockIdx.x).
// 8 waves K-split -> two-stage 64KB LDS reduce (XOR swizzle).
//   EPI=1: LSTM gates; block jb owns hidden units jb*16..+15, cols = g*16+u.
//   EPI=0: bias add + f32 store (logits).
// ---------------------------------------------------------------------------
template<int EPI, int GATHER1>
__global__ __launch_bounds__(512, 2) void gemm_ks_p(
    const float* __restrict__ a1F,
    const uint16_t* __restrict__ a1Hi, const uint16_t* __restrict__ a1Lo,
    const int* __restrict__ ridx, int rstride,
    const uint16_t* __restrict__ PH1, const uint8_t* __restrict__ PM1, int K1,
    const uint16_t* __restrict__ a2Hi, const uint16_t* __restrict__ a2Lo,
    const uint16_t* __restrict__ PH2, const uint8_t* __restrict__ PM2, int K2,
    const float* __restrict__ bih, const float* __restrict__ bhh,
    float* __restrict__ cState,
    uint16_t* __restrict__ hOutHi, uint16_t* __restrict__ hOutLo,
    const float* __restrict__ bias, float* __restrict__ Cout)
{
  __shared__ float red[4][64 * 64];   // exactly 64 KiB

  const int jb   = blockIdx.x;
  const int mb   = blockIdx.y;
  const int tid  = threadIdx.x;
  const int w    = tid >> 6;     // 0..7
  const int lane = tid & 63;
  const int lrow = lane & 31;
  const int lgrp = lane >> 5;

  f32x16 acc[2][2];
#pragma unroll
  for (int i = 0; i < 2; ++i)
#pragma unroll
    for (int j = 0; j < 2; ++j)
#pragma unroll
      for (int r = 0; r < 16; ++r) acc[i][j][r] = 0.0f;

  if (GATHER1) {
    const int tok0 = ridx[(size_t)(mb * 64 + lrow) * rstride];
    const int tok1 = ridx[(size_t)(mb * 64 + 32 + lrow) * rstride];
    run_phase64_p<true>(acc, a1F, nullptr, nullptr, tok0, tok1,
                        PH1, PM1, K1, EPI == 1, jb, mb, w, lrow, lgrp);
  } else {
    run_phase64_p<false>(acc, nullptr, a1Hi, a1Lo, 0, 0,
                         PH1, PM1, K1, EPI == 1, jb, mb, w, lrow, lgrp);
  }
  if (K2 > 0)
    run_phase64_p<false>(acc, nullptr, a2Hi, a2Lo, 0, 0,
                         PH2, PM2, K2, EPI == 1, jb, mb, w, lrow, lgrp);

  // two-stage partials -> LDS (XOR swizzle on low-5 col bits)
  const int wl = w & 3;
  if (w < 4) {
#pragma unroll
    for (int mf = 0; mf < 2; ++mf)
#pragma unroll
      for (int nf = 0; nf < 2; ++nf)
#pragma unroll
        for (int r = 0; r < 16; ++r) {
          const int row = mf * 32 + (r & 3) + 8 * (r >> 2) + 4 * lgrp;
          red[wl][row * 64 + nf * 32 + (lrow ^ (row & 31))] = acc[mf][nf][r];
        }
  }
  __syncthreads();
  if (w >= 4) {
#pragma unroll
    for (int mf = 0; mf < 2; ++mf)
#pragma unroll
      for (int nf = 0; nf < 2; ++nf)
#pragma unroll
        for (int r = 0; r < 16; ++r) {
          const int row = mf * 32 + (r & 3) + 8 * (r >> 2) + 4 * lgrp;
          red[wl][row * 64 + nf * 32 + (lrow ^ (row & 31))] += acc[mf][nf][r];
        }
  }
  __syncthreads();

  if constexpr (EPI == 1) {
    const int b    = tid & 63;        // row within tile
    const int brow = mb * 64 + b;     // global batch row
    const int uh   = tid >> 6;        // 0..7
#pragma unroll
    for (int q = 0; q < 2; ++q) {
      const int u = uh * 2 + q;       // 0..15
      float gs[4];
#pragma unroll
      for (int g = 0; g < 4; ++g) {
        const int cs = (g * 16 + u) ^ (b & 31);
        gs[g] = ((red[0][b * 64 + cs] + red[1][b * 64 + cs])
                 + red[2][b * 64 + cs]) + red[3][b * 64 + cs];
      }
      const int n = jb * 16 + u;
      float gi = gs[0] + bih[n]          + bhh[n];
      float gf = gs[1] + bih[H_ + n]     + bhh[H_ + n];
      float gg = gs[2] + bih[2 * H_ + n] + bhh[2 * H_ + n];
      float go = gs[3] + bih[3 * H_ + n] + bhh[3 * H_ + n];
      float si = 1.f / (1.f + expf(-gi));
      float sf = 1.f / (1.f + expf(-gf));
      float so = 1.f / (1.f + expf(-go));
      const size_t ci = (size_t)brow * H_ + n;
      float cv = sf * cState[ci] + si * tanhf(gg);
      cState[ci] = cv;
      float hv = so * tanhf(cv);
      uint16_t hh, hl;
      split2(hv, hh, hl);
      const size_t hoff = (size_t)((n >> 4) * 4 + (brow >> 5)) * 512
                        + (size_t)((n >> 3) & 1) * 256
                        + (size_t)(brow & 31) * 8 + (size_t)(n & 7);
      hOutHi[hoff] = hh;
      hOutLo[hoff] = hl;
    }
  } else {
    const int b  = tid & 63;
    const int bg = mb * 64 + b;
    const int ch = (tid >> 6) * 8;
#pragma unroll
    for (int q = 0; q < 8; ++q) {
      const int col = ch + q;
      const int cs  = col ^ (b & 31);
      float v = ((red[0][b * 64 + cs] + red[1][b * 64 + cs])
                 + red[2][b * 64 + cs]) + red[3][b * 64 + cs];
      Cout[(size_t)bg * V_ + jb * 64 + col] = v + bias[jb * 64 + col];
    }
  }
}

// ===========================================================================
// FALLBACK: r7 f32-B GEMM, N=32 tile, verbatim (only if ws can't hold panels).
// ===========================================================================
template<bool GATHER>
__device__ __forceinline__ void run_phase_f(
    f32x16 (&acc)[4],
    const float* __restrict__ aF,
    const uint16_t* __restrict__ aHi, const uint16_t* __restrict__ aLo,
    const int* __restrict__ ridx, int rstride,
    const float* __restrict__ W, int K, bool gateRe,
    int jb, int w, int lrow, int lgrp)
{
  const int nFS = K >> 7;
  const int wrow = gateRe ? ((lrow >> 3) * H_ + jb * 8 + (lrow & 7))
                          : (jb * 32 + lrow);
  const float* bptr = W + (size_t)wrow * K + lgrp * 8;

  size_t aoff0, aoff1, aoff2, aoff3;
  if (GATHER) {
    aoff0 = (size_t)ridx[(size_t)(lrow)      * rstride] * E_ + lgrp * 8;
    aoff1 = (size_t)ridx[(size_t)(32 + lrow) * rstride] * E_ + lgrp * 8;
    aoff2 = (size_t)ridx[(size_t)(64 + lrow) * rstride] * E_ + lgrp * 8;
    aoff3 = (size_t)ridx[(size_t)(96 + lrow) * rstride] * E_ + lgrp * 8;
  } else {
    aoff0 = (size_t)lgrp * 256 + (size_t)lrow * 8;
    aoff1 = aoff0 + 512;
    aoff2 = aoff0 + 1024;
    aoff3 = aoff0 + 1536;
  }

  float4 bR0[2], bR1[2];
  float4 gR0[2][2], gR1[2][2], gR2[2][2], gR3[2][2];
  bf16x8 sh0[2], sh1[2], sh2[2], sh3[2], sl0[2], sl1[2], sl2[2], sl3[2];

#define LOADFS(BUF, KS)                                                      \
  {                                                                          \
    const float* bp = bptr + (size_t)(KS) * 16;                              \
    bR0[BUF] = ((const float4*)bp)[0];                                       \
    bR1[BUF] = ((const float4*)bp)[1];                                       \
    if (GATHER) {                                                            \
      const float* a0 = aF + aoff0 + (size_t)(KS) * 16;                      \
      const float* a1 = aF + aoff1 + (size_t)(KS) * 16;                      \
      const float* a2 = aF + aoff2 + (size_t)(KS) * 16;                      \
      const float* a3 = aF + aoff3 + (size_t)(KS) * 16;                      \
      gR0[BUF][0] = ((const float4*)a0)[0]; gR0[BUF][1] = ((const float4*)a0)[1]; \
      gR1[BUF][0] = ((const float4*)a1)[0]; gR1[BUF][1] = ((const float4*)a1)[1]; \
      gR2[BUF][0] = ((const float4*)a2)[0]; gR2[BUF][1] = ((const float4*)a2)[1]; \
      gR3[BUF][0] = ((const float4*)a3)[0]; gR3[BUF][1] = ((const float4*)a3)[1]; \
    } else {                                                                 \
      size_t o0 = aoff0 + (size_t)(KS) * 2048;                               \
      size_t o1 = aoff1 + (size_t)(KS) * 2048;                               \
      size_t o2 = aoff2 + (size_t)(KS) * 2048;                               \
      size_t o3 = aoff3 + (size_t)(KS) * 2048;                               \
      sh0[BUF] = *(const bf16x8*)(aHi + o0); sl0[BUF] = *(const bf16x8*)(aLo + o0); \
      sh1[BUF] = *(const bf16x8*)(aHi + o1); sl1[BUF] = *(const bf16x8*)(aLo + o1); \
      sh2[BUF] = *(const bf16x8*)(aHi + o2); sl2[BUF] = *(const bf16x8*)(aLo + o2); \
      sh3[BUF] = *(const bf16x8*)(aHi + o3); sl3[BUF] = *(const bf16x8*)(aLo + o3); \
    }                                                                        \
  }

#define COMPFS(BUF)                                                          \
  {                                                                          \
    bf16x8 bh, bl;                                                           \
    splitpack(bR0[BUF], bR1[BUF], bh, bl);                                   \
    bf16x8 ah, al;                                                           \
    if (GATHER) splitpack(gR0[BUF][0], gR0[BUF][1], ah, al);                 \
    else { ah = sh0[BUF]; al = sl0[BUF]; }                                   \
    acc[0] = MFMA_(ah, bh, acc[0]);                                          \
    acc[0] = MFMA_(ah, bl, acc[0]);                                          \
    acc[0] = MFMA_(al, bh, acc[0]);                                          \
    if (GATHER) splitpack(gR1[BUF][0], gR1[BUF][1], ah, al);                 \
    else { ah = sh1[BUF]; al = sl1[BUF]; }                                   \
    acc[1] = MFMA_(ah, bh, acc[1]);                                          \
    acc[1] = MFMA_(ah, bl, acc[1]);                                          \
    acc[1] = MFMA_(al, bh, acc[1]);                                          \
    if (GATHER) splitpack(gR2[BUF][0], gR2[BUF][1], ah, al);                 \
    else { ah = sh2[BUF]; al = sl2[BUF]; }                                   \
    acc[2] = MFMA_(ah, bh, acc[2]);                                          \
    acc[2] = MFMA_(ah, bl, acc[2]);                                          \
    acc[2] = MFMA_(al, bh, acc[2]);                                          \
    if (GATHER) splitpack(gR3[BUF][0], gR3[BUF][1], ah, al);                 \
    else { ah = sh3[BUF]; al = sl3[BUF]; }                                   \
    acc[3] = MFMA_(ah, bh, acc[3]);                                          \
    acc[3] = MFMA_(ah, bl, acc[3]);                                          \
    acc[3] = MFMA_(al, bh, acc[3]);                                          \
  }

  int ks = w;
  LOADFS(0, ks); ks += 8;
  int rem = nFS;
  while (rem >= 2) {
    LOADFS(1, ks); ks += 8;
    COMPFS(0);
    if (rem > 2) { LOADFS(0, ks); ks += 8; }
    COMPFS(1);
    rem -= 2;
  }
#undef LOADFS
#undef COMPFS
}

template<int EPI, int GATHER1>
__global__ __launch_bounds__(512, 2) void gemm_ks_f(
    const float* __restrict__ a1F,
    const uint16_t* __restrict__ a1Hi, const uint16_t* __restrict__ a1Lo,
    const int* __restrict__ ridx, int rstride,
    const float* __restrict__ W1, int K1,
    const uint16_t* __restrict__ a2Hi, const uint16_t* __restrict__ a2Lo,
    const float* __restrict__ W2, int K2,
    const float* __restrict__ bih, const float* __restrict__ bhh,
    float* __restrict__ cState,
    uint16_t* __restrict__ hOutHi, uint16_t* __restrict__ hOutLo,
    const float* __restrict__ bias, float* __restrict__ Cout)
{
  __shared__ float red[4][128 * 32];

  const int jb   = blockIdx.x;
  const int tid  = threadIdx.x;
  const int w    = tid >> 6;
  const int lane = tid & 63;
  const int lrow = lane & 31;
  const int lgrp = lane >> 5;

  f32x16 acc[4];
#pragma unroll
  for (int mf = 0; mf < 4; ++mf)
#pragma unroll
    for (int r = 0; r < 16; ++r) acc[mf][r] = 0.0f;

  run_phase_f<GATHER1 != 0>(acc, a1F, a1Hi, a1Lo, ridx, rstride,
                            W1, K1, EPI == 1, jb, w, lrow, lgrp);
  if (K2 > 0)
    run_phase_f<false>(acc, nullptr, a2Hi, a2Lo, nullptr, 0,
                       W2, K2, EPI == 1, jb, w, lrow, lgrp);

  const int wl = w & 3;
  if (w < 4) {
#pragma unroll
    for (int mf = 0; mf < 4; ++mf)
#pragma unroll
      for (int r = 0; r < 16; ++r) {
        const int row = mf * 32 + (r & 3) + 8 * (r >> 2) + 4 * lgrp;
        red[wl][row * 32 + (lrow ^ (row & 31))] = acc[mf][r];
      }
  }
  __syncthreads();
  if (w >= 4) {
#pragma unroll
    for (int mf = 0; mf < 4; ++mf)
#pragma unroll
      for (int r = 0; r < 16; ++r) {
        const int row = mf * 32 + (r & 3) + 8 * (r >> 2) + 4 * lgrp;
        red[wl][row * 32 + (lrow ^ (row & 31))] += acc[mf][r];
      }
  }
  __syncthreads();

  if constexpr (EPI == 1) {
    const int b  = tid & 127;
    const int uh = (tid >> 7) * 2;
#pragma unroll
    for (int q = 0; q < 2; ++q) {
      const int u = uh + q;
      float gs[4];
#pragma unroll
      for (int g = 0; g < 4; ++g) {
        const int cs = (g * 8 + u) ^ (b & 31);
        gs[g] = ((red[0][b * 32 + cs] + red[1][b * 32 + cs])
                 + red[2][b * 32 + cs]) + red[3][b * 32 + cs];
      }
      const int n = jb * 8 + u;
      float gi = gs[0] + bih[n]          + bhh[n];
      float gf = gs[1] + bih[H_ + n]     + bhh[H_ + n];
      float gg = gs[2] + bih[2 * H_ + n] + bhh[2 * H_ + n];
      float go = gs[3] + bih[3 * H_ + n] + bhh[3 * H_ + n];
      float si = 1.f / (1.f + expf(-gi));
      float sf = 1.f / (1.f + expf(-gf));
      float so = 1.f / (1.f + expf(-go));
      const size_t ci = (size_t)b * H_ + n;
      float cv = sf * cState[ci] + si * tanhf(gg);
      cState[ci] = cv;
      float hv = so * tanhf(cv);
      uint16_t hh, hl;
      split2(hv, hh, hl);
      const size_t hoff = (size_t)((n >> 4) * 4 + (b >> 5)) * 512
                        + (size_t)((n >> 3) & 1) * 256
                        + (size_t)(b & 31) * 8 + (size_t)(n & 7);
      hOutHi[hoff] = hh;
      hOutLo[hoff] = hl;
    }
  } else {
    const int b  = tid & 127;
    const int ch = (tid >> 7) * 8;
#pragma unroll
    for (int q = 0; q < 8; ++q) {
      const int col = ch + q;
      const int cs  = col ^ (b & 31);
      float v = ((red[0][b * 32 + cs] + red[1][b * 32 + cs])
                 + red[2][b * 32 + cs]) + red[3][b * 32 + cs];
      Cout[(size_t)b * V_ + jb * 32 + col] = v + bias[jb * 32 + col];
    }
  }
}

// ---------------------------------------------------------------------------
// categorical sampling (verbatim from passing rounds 3-7,10)
// ---------------------------------------------------------------------------
__global__ __launch_bounds__(256) void sample_kernel(
    const float* __restrict__ logits, const uint32_t* __restrict__ keys,
    int t, int* __restrict__ out, int col)
{
  const int b = blockIdx.x;
  const int tid = threadIdx.x;
  const uint32_t k0 = keys[2 * t];
  const uint32_t k1 = keys[2 * t + 1];
  const float* lrow = logits + (size_t)b * V_;

  float best = -3.4e38f;
  int bestIdx = 0;
  for (int v = tid; v < V_; v += 256) {
    uint32_t j = (uint32_t)(b * V_ + v);
    uint32_t o0, o1;
    threefry2x32(k0, k1, 0u, j, o0, o1);
    uint32_t bits = o0 ^ o1;
    float f = __uint_as_float((bits >> 9) | 0x3f800000u) - 1.0f;
    float u = fmaxf(1.17549435e-38f, f + 1.17549435e-38f);
    float t1 = (float)log((double)u);
    float t2 = -t1;
    float t3 = (float)log((double)t2);
    float val = (-t3) + lrow[v];
    if (val > best) { best = val; bestIdx = v; }
  }

  __shared__ float sv[256];
  __shared__ int   si[256];
  sv[tid] = best; si[tid] = bestIdx;
  __syncthreads();
  for (int s = 128; s > 0; s >>= 1) {
    if (tid < s) {
      float v2 = sv[tid + s]; int i2 = si[tid + s];
      if (v2 > sv[tid] || (v2 == sv[tid] && i2 < si[tid])) { sv[tid] = v2; si[tid] = i2; }
    }
    __syncthreads();
  }
  if (tid == 0) out[b * S_ + col] = si[0];
}

// ---------------------------------------------------------------------------
extern "C" void kernel_launch(void* const* d_in, const int* in_sizes, int n_in,
                              void* d_out, int out_size, void* d_ws, size_t ws_size,
                              hipStream_t stream) {
  const int*   x    = (const int*)  d_in[0];
  const float* emb  = (const float*)d_in[3];
  const float* Wih0 = (const float*)d_in[4];
  const float* Whh0 = (const float*)d_in[5];
  const float* bih0 = (const float*)d_in[6];
  const float* bhh0 = (const float*)d_in[7];
  const float* Wih1 = (const float*)d_in[8];
  const float* Whh1 = (const float*)d_in[9];
  const float* bih1 = (const float*)d_in[10];
  const float* bhh1 = (const float*)d_in[11];
  const float* Wlin = (const float*)d_in[12];
  const float* blin = (const float*)d_in[13];
  int* out = (int*)d_out;

  // ---- workspace carve-up ----
  char* wp = (char*)d_ws;
  size_t o = 0;
  auto alloc = [&](size_t bytes) {
    void* p = wp + o; o += (bytes + 255) & ~(size_t)255; return p;
  };
  uint32_t* keys   = (uint32_t*)alloc(512);
  float*    logits = (float*)   alloc((size_t)B_ * V_ * 4);
  float*    c0     = (float*)   alloc((size_t)B_ * H_ * 4);   // zero-block start
  float*    c1     = (float*)   alloc((size_t)B_ * H_ * 4);
  uint16_t* hS0hi[2]; uint16_t* hS0lo[2]; uint16_t* hS1hi[2]; uint16_t* hS1lo[2];
  for (int i = 0; i < 2; ++i) hS0hi[i] = (uint16_t*)alloc((size_t)B_ * H_ * 2);
  for (int i = 0; i < 2; ++i) hS0lo[i] = (uint16_t*)alloc((size_t)B_ * H_ * 2);
  for (int i = 0; i < 2; ++i) hS1hi[i] = (uint16_t*)alloc((size_t)B_ * H_ * 2);
  for (int i = 0; i < 2; ++i) hS1lo[i] = (uint16_t*)alloc((size_t)B_ * H_ * 2);
  size_t zeroBytes = (size_t)((char*)hS1lo[1] + (size_t)B_ * H_ * 2 - (char*)c0);

  // panel allocations (only valid if ws_size allows)
  const size_t nIh0 = (size_t)H4_ * E_;    // 4.19M
  const size_t nHh  = (size_t)H4_ * H_;    // 16.78M (x3)
  const size_t nLin = (size_t)V_ * H_;     // 16.38M
  uint16_t* PHih0 = (uint16_t*)alloc(nIh0 * 2);
  uint8_t*  PMih0 = (uint8_t*) alloc(nIh0);
  uint16_t* PHhh0 = (uint16_t*)alloc(nHh * 2);
  uint8_t*  PMhh0 = (uint8_t*) alloc(nHh);
  uint16_t* PHih1 = (uint16_t*)alloc(nHh * 2);
  uint8_t*  PMih1 = (uint8_t*) alloc(nHh);
  uint16_t* PHhh1 = (uint16_t*)alloc(nHh * 2);
  uint8_t*  PMhh1 = (uint8_t*) alloc(nHh);
  uint16_t* PHlin = (uint16_t*)alloc(nLin * 2);
  uint8_t*  PMlin = (uint8_t*) alloc(nLin);
  const bool usePacked = (o <= ws_size);

  hipMemsetAsync(c0, 0, zeroBytes, stream);
  keys_kernel<<<1, 64, 0, stream>>>(keys);
  copy_prefix<<<(B_ * GIVEN_) / 256, 256, 0, stream>>>(x, out);

  if (usePacked) {
    pack3<<<(int)((nIh0 / 8 + 255) / 256), 256, 0, stream>>>(Wih0, PHih0, PMih0, (int)(nIh0 / 8));
    pack3<<<(int)((nHh / 8 + 255) / 256), 256, 0, stream>>>(Whh0, PHhh0, PMhh0, (int)(nHh / 8));
    pack3<<<(int)((nHh / 8 + 255) / 256), 256, 0, stream>>>(Wih1, PHih1, PMih1, (int)(nHh / 8));
    pack3<<<(int)((nHh / 8 + 255) / 256), 256, 0, stream>>>(Whh1, PHhh1, PMhh1, (int)(nHh / 8));
    pack3<<<(int)((nLin / 8 + 255) / 256), 256, 0, stream>>>(Wlin, PHlin, PMlin, (int)(nLin / 8));
  }

  dim3 gridLSTM64(H4_ / 64, 2);   // (128, 2)
  dim3 gridLogit64(V_ / 64, 2);   // (125, 2)

  int p = 0;
  auto lstm_step = [&](const int* ridx) {
    if (usePacked) {
      gemm_ks_p<1, 1><<<gridLSTM64, 512, 0, stream>>>(
          emb, nullptr, nullptr, ridx, S_, PHih0, PMih0, E_,
          hS0hi[p], hS0lo[p], PHhh0, PMhh0, H_,
          bih0, bhh0, c0, hS0hi[p ^ 1], hS0lo[p ^ 1], nullptr, nullptr);
      gemm_ks_p<1, 0><<<gridLSTM64, 512, 0, stream>>>(
          nullptr, hS0hi[p ^ 1], hS0lo[p ^ 1], nullptr, 0, PHih1, PMih1, H_,
          hS1hi[p], hS1lo[p], PHhh1, PMhh1, H_,
          bih1, bhh1, c1, hS1hi[p ^ 1], hS1lo[p ^ 1], nullptr, nullptr);
    } else {
      gemm_ks_f<1, 1><<<H_ / 8, 512, 0, stream>>>(
          emb, nullptr, nullptr, ridx, S_, Wih0, E_,
          hS0hi[p], hS0lo[p], Whh0, H_,
          bih0, bhh0, c0, hS0hi[p ^ 1], hS0lo[p ^ 1], nullptr, nullptr);
      gemm_ks_f<1, 0><<<H_ / 8, 512, 0, stream>>>(
          nullptr, hS0hi[p ^ 1], hS0lo[p ^ 1], nullptr, 0, Wih1, H_,
          hS1hi[p], hS1lo[p], Whh1, H_,
          bih1, bhh1, c1, hS1hi[p ^ 1], hS1lo[p ^ 1], nullptr, nullptr);
    }
    p ^= 1;
  };

  // teacher forcing
  for (int t = 0; t < GIVEN_; ++t) {
    lstm_step(x + t);
  }

  // rollout
  for (int t = 0; t < S_ - GIVEN_; ++t) {
    const int* ridx = (t == 0) ? (x + (GIVEN_ - 1)) : (out + (GIVEN_ + t - 1));
    lstm_step(ridx);
    if (usePacked) {
      gemm_ks_p<0, 0><<<gridLogit64, 512, 0, stream>>>(
          nullptr, hS1hi[p], hS1lo[p], nullptr, 0, PHlin, PMlin, H_,
          nullptr, nullptr, nullptr, nullptr, 0,
          nullptr, nullptr, nullptr, nullptr, nullptr, blin, logits);
    } else {
      gemm_ks_f<0, 0><<<V_ / 32, 512, 0, stream>>>(
          nullptr, hS1hi[p], hS1lo[p], nullptr, 0, Wlin, H_,
          nullptr, nullptr, nullptr, 0,
          nullptr, nullptr, nullptr, nullptr, nullptr, blin, logits);
    }
    sample_kernel<<<B_, 256, 0, stream>>>(logits, keys, t, out, GIVEN_ + t);
  }
}

// Round 12
// 13265.051 us; speedup vs baseline: 1.0586x; 1.0586x over previous
//
#include <hip/hip_runtime.h>
#include <stdint.h>
#include <math.h>

// Problem constants (fixed by setup_inputs)
#define B_     128
#define S_     128
#define V_     8000
#define E_     512
#define H_     2048
#define H4_    8192
#define GIVEN_ 64

typedef __bf16 bf16x8 __attribute__((ext_vector_type(8)));
typedef float  f32x16 __attribute__((ext_vector_type(16)));
typedef short  short8 __attribute__((ext_vector_type(8)));

// ---------------------------------------------------------------------------
// Threefry-2x32 (20 rounds) — exact JAX semantics (verified passing r3-r7,r10)
// ---------------------------------------------------------------------------
__device__ __forceinline__ uint32_t rotl32(uint32_t v, int d) {
  return (v << d) | (v >> (32 - d));
}

__device__ __forceinline__ void threefry2x32(uint32_t k0, uint32_t k1,
                                             uint32_t x0, uint32_t x1,
                                             uint32_t& o0, uint32_t& o1) {
  uint32_t k2 = k0 ^ k1 ^ 0x1BD11BDAu;
  x0 += k0; x1 += k1;
#define TF_RND(R) { x0 += x1; x1 = rotl32(x1, (R)); x1 ^= x0; }
  TF_RND(13) TF_RND(15) TF_RND(26) TF_RND(6)
  x0 += k1; x1 += k2 + 1u;
  TF_RND(17) TF_RND(29) TF_RND(16) TF_RND(24)
  x0 += k2; x1 += k0 + 2u;
  TF_RND(13) TF_RND(15) TF_RND(26) TF_RND(6)
  x0 += k0; x1 += k1 + 3u;
  TF_RND(17) TF_RND(29) TF_RND(16) TF_RND(24)
  x0 += k1; x1 += k2 + 4u;
  TF_RND(13) TF_RND(15) TF_RND(26) TF_RND(6)
  x0 += k2; x1 += k0 + 5u;
#undef TF_RND
  o0 = x0; o1 = x1;
}

__global__ void keys_kernel(uint32_t* __restrict__ keys) {
  int t = threadIdx.x;  // 0..63
  uint32_t o0, o1;
  threefry2x32(0u, 1u, 0u, (uint32_t)t, o0, o1);
  keys[2 * t]     = o0;
  keys[2 * t + 1] = o1;
}

__global__ void copy_prefix(const int* __restrict__ x, int* __restrict__ out) {
  int idx = blockIdx.x * blockDim.x + threadIdx.x;
  int b = idx >> 6;
  int s = idx & 63;
  out[b * S_ + s] = x[b * S_ + s];
}

// split f32 -> hi/lo bf16 (truncation; identical math to passing rounds)
__device__ __forceinline__ void split2(float x, uint16_t& hi, uint16_t& lo) {
  uint32_t xb = __float_as_uint(x);
  hi = (uint16_t)(xb >> 16);
  float l = x - __uint_as_float(xb & 0xFFFF0000u);
  lo = (uint16_t)(__float_as_uint(l) >> 16);
}

__device__ __forceinline__ void splitpack(float4 a, float4 b,
                                          bf16x8& hi, bf16x8& lo) {
  float e[8] = {a.x, a.y, a.z, a.w, b.x, b.y, b.z, b.w};
  short8 h, l;
#pragma unroll
  for (int j = 0; j < 8; ++j) {
    uint16_t h16, l16;
    split2(e[j], h16, l16);
    h[j] = (short)h16;
    l[j] = (short)l16;
  }
  hi = __builtin_bit_cast(bf16x8, h);
  lo = __builtin_bit_cast(bf16x8, l);
}

// unpack packed-3B weight frag: hi bf16x8 (direct) + 8 mid-bytes -> lo bf16x8
__device__ __forceinline__ void unpack3(short8 hv, uint2 m, bf16x8& bh, bf16x8& bl) {
  short8 lv;
#pragma unroll
  for (int j = 0; j < 8; ++j) {
    uint32_t hbits = ((uint32_t)(uint16_t)hv[j]) << 16;
    uint32_t mbyte = ((j < 4 ? (m.x >> (8 * j)) : (m.y >> (8 * (j - 4)))) & 0xFFu);
    float xf = __uint_as_float(hbits | (mbyte << 8));
    float lf = xf - __uint_as_float(hbits);
    lv[j] = (short)(__float_as_uint(lf) >> 16);
  }
  bh = __builtin_bit_cast(bf16x8, hv);
  bl = __builtin_bit_cast(bf16x8, lv);
}

// pack f32 weights -> PH (top 16 bits) + PM (mantissa bits 8..16)
__global__ __launch_bounds__(256) void pack3(
    const float* __restrict__ W, uint16_t* __restrict__ PH,
    uint8_t* __restrict__ PM, int n8)
{
  int i = blockIdx.x * 256 + threadIdx.x;   // handles 8 elems
  if (i >= n8) return;
  float4 a = ((const float4*)W)[2 * i];
  float4 b = ((const float4*)W)[2 * i + 1];
  float e[8] = {a.x, a.y, a.z, a.w, b.x, b.y, b.z, b.w};
  short8 h;
  uint32_t mlo = 0, mhi = 0;
#pragma unroll
  for (int j = 0; j < 8; ++j) {
    uint32_t xb = __float_as_uint(e[j]);
    h[j] = (short)(xb >> 16);
    uint32_t mb = (xb >> 8) & 0xFFu;
    if (j < 4) mlo |= mb << (8 * j);
    else       mhi |= mb << (8 * (j - 4));
  }
  *(short8*)&PH[(size_t)i * 8] = h;
  *(uint2*)&PM[(size_t)i * 8] = make_uint2(mlo, mhi);
}

#define MFMA_(a, b, c) __builtin_amdgcn_mfma_f32_32x32x16_bf16(a, b, c, 0, 0, 0)

// ===========================================================================
// PACKED-B GEMM phase (r10 geometry: M=128 x N=32): acc[4] += A(128 x K) @ W^T
// for this block's 32 output cols. B from PH/PM 3-byte panels, **4-deep
// prefetch**; A (gathered-f32 emb or pre-split staged-h) 2-deep.
// 8 waves K-split: wave w takes k16-steps w, w+8, ...
// staged-h layout: elem(b,n) at ((n>>4)*4+(b>>5))*512+((n>>3)&1)*256+(b&31)*8+(n&7)
// ===========================================================================
template<bool GATHER>
__device__ __forceinline__ void run_phase_p(
    f32x16 (&acc)[4],
    const float* __restrict__ aF,
    const uint16_t* __restrict__ aHi, const uint16_t* __restrict__ aLo,
    const int* __restrict__ ridx, int rstride,
    const uint16_t* __restrict__ PH, const uint8_t* __restrict__ PM,
    int K, bool gateRe, int jb, int w, int lrow, int lgrp)
{
  const int nFS = K >> 7;          // 4 or 16 (multiple of 4)
  const int wrow = gateRe ? ((lrow >> 3) * H_ + jb * 8 + (lrow & 7))
                          : (jb * 32 + lrow);
  const size_t bbase = (size_t)wrow * K + lgrp * 8;

  size_t aoff0, aoff1, aoff2, aoff3;
  if (GATHER) {
    aoff0 = (size_t)ridx[(size_t)(lrow)      * rstride] * E_ + lgrp * 8;
    aoff1 = (size_t)ridx[(size_t)(32 + lrow) * rstride] * E_ + lgrp * 8;
    aoff2 = (size_t)ridx[(size_t)(64 + lrow) * rstride] * E_ + lgrp * 8;
    aoff3 = (size_t)ridx[(size_t)(96 + lrow) * rstride] * E_ + lgrp * 8;
  } else {
    aoff0 = (size_t)lgrp * 256 + (size_t)lrow * 8;
    aoff1 = aoff0 + 512;
    aoff2 = aoff0 + 1024;
    aoff3 = aoff0 + 1536;
  }

  // 4-deep B buffers, 2-deep A buffers (all statically indexed)
  short8 bH[4]; uint2 bM[4];
  float4 gR0[2][2], gR1[2][2], gR2[2][2], gR3[2][2];
  bf16x8 sh0[2], sh1[2], sh2[2], sh3[2], sl0[2], sl1[2], sl2[2], sl3[2];

#define BLOAD(BUF, KS)                                                       \
  {                                                                          \
    const size_t bo = bbase + (size_t)(KS) * 16;                             \
    bH[BUF] = *(const short8*)(PH + bo);                                     \
    bM[BUF] = *(const uint2*)(PM + bo);                                      \
  }

#define ALOAD(BUF, KS)                                                       \
  {                                                                          \
    if (GATHER) {                                                            \
      const float* a0 = aF + aoff0 + (size_t)(KS) * 16;                      \
      const float* a1 = aF + aoff1 + (size_t)(KS) * 16;                      \
      const float* a2 = aF + aoff2 + (size_t)(KS) * 16;                      \
      const float* a3 = aF + aoff3 + (size_t)(KS) * 16;                      \
      gR0[BUF][0] = ((const float4*)a0)[0]; gR0[BUF][1] = ((const float4*)a0)[1]; \
      gR1[BUF][0] = ((const float4*)a1)[0]; gR1[BUF][1] = ((const float4*)a1)[1]; \
      gR2[BUF][0] = ((const float4*)a2)[0]; gR2[BUF][1] = ((const float4*)a2)[1]; \
      gR3[BUF][0] = ((const float4*)a3)[0]; gR3[BUF][1] = ((const float4*)a3)[1]; \
    } else {                                                                 \
      size_t o0 = aoff0 + (size_t)(KS) * 2048;                               \
      size_t o1 = aoff1 + (size_t)(KS) * 2048;                               \
      size_t o2 = aoff2 + (size_t)(KS) * 2048;                               \
      size_t o3 = aoff3 + (size_t)(KS) * 2048;                               \
      sh0[BUF] = *(const bf16x8*)(aHi + o0); sl0[BUF] = *(const bf16x8*)(aLo + o0); \
      sh1[BUF] = *(const bf16x8*)(aHi + o1); sl1[BUF] = *(const bf16x8*)(aLo + o1); \
      sh2[BUF] = *(const bf16x8*)(aHi + o2); sl2[BUF] = *(const bf16x8*)(aLo + o2); \
      sh3[BUF] = *(const bf16x8*)(aHi + o3); sl3[BUF] = *(const bf16x8*)(aLo + o3); \
    }                                                                        \
  }

#define COMP(BB, AB)                                                         \
  {                                                                          \
    bf16x8 bh, bl;                                                           \
    unpack3(bH[BB], bM[BB], bh, bl);                                         \
    bf16x8 ah, al;                                                           \
    if (GATHER) splitpack(gR0[AB][0], gR0[AB][1], ah, al);                   \
    else { ah = sh0[AB]; al = sl0[AB]; }                                     \
    acc[0] = MFMA_(ah, bh, acc[0]);                                          \
    acc[0] = MFMA_(ah, bl, acc[0]);                                          \
    acc[0] = MFMA_(al, bh, acc[0]);                                          \
    if (GATHER) splitpack(gR1[AB][0], gR1[AB][1], ah, al);                   \
    else { ah = sh1[AB]; al = sl1[AB]; }                                     \
    acc[1] = MFMA_(ah, bh, acc[1]);                                          \
    acc[1] = MFMA_(ah, bl, acc[1]);                                          \
    acc[1] = MFMA_(al, bh, acc[1]);                                          \
    if (GATHER) splitpack(gR2[AB][0], gR2[AB][1], ah, al);                   \
    else { ah = sh2[AB]; al = sl2[AB]; }                                     \
    acc[2] = MFMA_(ah, bh, acc[2]);                                          \
    acc[2] = MFMA_(ah, bl, acc[2]);                                          \
    acc[2] = MFMA_(al, bh, acc[2]);                                          \
    if (GATHER) splitpack(gR3[AB][0], gR3[AB][1], ah, al);                   \
    else { ah = sh3[AB]; al = sl3[AB]; }                                     \
    acc[3] = MFMA_(ah, bh, acc[3]);                                          \
    acc[3] = MFMA_(ah, bl, acc[3]);                                          \
    acc[3] = MFMA_(al, bh, acc[3]);                                          \
  }

  // prologue: B 4 steps ahead, A 2 steps ahead (nFS >= 4 always)
  BLOAD(0, w); BLOAD(1, w + 8); BLOAD(2, w + 16); BLOAD(3, w + 24);
  ALOAD(0, w); ALOAD(1, w + 8);
  for (int it = 0; it < nFS; it += 4) {
    const int kb = w + it * 8;
    COMP(0, 0);
    if (it + 4 < nFS) BLOAD(0, kb + 32);
    if (it + 2 < nFS) ALOAD(0, kb + 16);
    COMP(1, 1);
    if (it + 5 < nFS) BLOAD(1, kb + 40);
    if (it + 3 < nFS) ALOAD(1, kb + 24);
    COMP(2, 0);
    if (it + 6 < nFS) BLOAD(2, kb + 48);
    if (it + 4 < nFS) ALOAD(0, kb + 32);
    COMP(3, 1);
    if (it + 7 < nFS) BLOAD(3, kb + 56);
    if (it + 5 < nFS) ALOAD(1, kb + 40);
  }
#undef BLOAD
#undef ALOAD
#undef COMP
}

// ---------------------------------------------------------------------------
// Fused dual-GEMM + epilogue (r10 structure, packed-B). M=128 x N=32 tile.
// ---------------------------------------------------------------------------
template<int EPI, int GATHER1>
__global__ __launch_bounds__(512, 2) void gemm_ks_p(
    const float* __restrict__ a1F,
    const uint16_t* __restrict__ a1Hi, const uint16_t* __restrict__ a1Lo,
    const int* __restrict__ ridx, int rstride,
    const uint16_t* __restrict__ PH1, const uint8_t* __restrict__ PM1, int K1,
    const uint16_t* __restrict__ a2Hi, const uint16_t* __restrict__ a2Lo,
    const uint16_t* __restrict__ PH2, const uint8_t* __restrict__ PM2, int K2,
    const float* __restrict__ bih, const float* __restrict__ bhh,
    float* __restrict__ cState,
    uint16_t* __restrict__ hOutHi, uint16_t* __restrict__ hOutLo,
    const float* __restrict__ bias, float* __restrict__ Cout)
{
  __shared__ float red[4][128 * 32];   // 64 KiB

  const int jb   = blockIdx.x;
  const int tid  = threadIdx.x;
  const int w    = tid >> 6;
  const int lane = tid & 63;
  const int lrow = lane & 31;
  const int lgrp = lane >> 5;

  f32x16 acc[4];
#pragma unroll
  for (int mf = 0; mf < 4; ++mf)
#pragma unroll
    for (int r = 0; r < 16; ++r) acc[mf][r] = 0.0f;

  run_phase_p<GATHER1 != 0>(acc, a1F, a1Hi, a1Lo, ridx, rstride,
                            PH1, PM1, K1, EPI == 1, jb, w, lrow, lgrp);
  if (K2 > 0)
    run_phase_p<false>(acc, nullptr, a2Hi, a2Lo, nullptr, 0,
                       PH2, PM2, K2, EPI == 1, jb, w, lrow, lgrp);

  const int wl = w & 3;
  if (w < 4) {
#pragma unroll
    for (int mf = 0; mf < 4; ++mf)
#pragma unroll
      for (int r = 0; r < 16; ++r) {
        const int row = mf * 32 + (r & 3) + 8 * (r >> 2) + 4 * lgrp;
        red[wl][row * 32 + (lrow ^ (row & 31))] = acc[mf][r];
      }
  }
  __syncthreads();
  if (w >= 4) {
#pragma unroll
    for (int mf = 0; mf < 4; ++mf)
#pragma unroll
      for (int r = 0; r < 16; ++r) {
        const int row = mf * 32 + (r & 3) + 8 * (r >> 2) + 4 * lgrp;
        red[wl][row * 32 + (lrow ^ (row & 31))] += acc[mf][r];
      }
  }
  __syncthreads();

  if constexpr (EPI == 1) {
    const int b  = tid & 127;
    const int uh = (tid >> 7) * 2;   // 0,2,4,6
#pragma unroll
    for (int q = 0; q < 2; ++q) {
      const int u = uh + q;
      float gs[4];
#pragma unroll
      for (int g = 0; g < 4; ++g) {
        const int cs = (g * 8 + u) ^ (b & 31);
        gs[g] = ((red[0][b * 32 + cs] + red[1][b * 32 + cs])
                 + red[2][b * 32 + cs]) + red[3][b * 32 + cs];
      }
      const int n = jb * 8 + u;
      float gi = gs[0] + bih[n]          + bhh[n];
      float gf = gs[1] + bih[H_ + n]     + bhh[H_ + n];
      float gg = gs[2] + bih[2 * H_ + n] + bhh[2 * H_ + n];
      float go = gs[3] + bih[3 * H_ + n] + bhh[3 * H_ + n];
      float si = 1.f / (1.f + expf(-gi));
      float sf = 1.f / (1.f + expf(-gf));
      float so = 1.f / (1.f + expf(-go));
      const size_t ci = (size_t)b * H_ + n;
      float cv = sf * cState[ci] + si * tanhf(gg);
      cState[ci] = cv;
      float hv = so * tanhf(cv);
      uint16_t hh, hl;
      split2(hv, hh, hl);
      const size_t hoff = (size_t)((n >> 4) * 4 + (b >> 5)) * 512
                        + (size_t)((n >> 3) & 1) * 256
                        + (size_t)(b & 31) * 8 + (size_t)(n & 7);
      hOutHi[hoff] = hh;
      hOutLo[hoff] = hl;
    }
  } else {
    const int b  = tid & 127;
    const int ch = (tid >> 7) * 8;
#pragma unroll
    for (int q = 0; q < 8; ++q) {
      const int col = ch + q;
      const int cs  = col ^ (b & 31);
      float v = ((red[0][b * 32 + cs] + red[1][b * 32 + cs])
                 + red[2][b * 32 + cs]) + red[3][b * 32 + cs];
      Cout[(size_t)b * V_ + jb * 32 + col] = v + bias[jb * 32 + col];
    }
  }
}

// ===========================================================================
// FALLBACK: r7 f32-B GEMM, N=32 tile, verbatim (only if ws can't hold panels).
// ===========================================================================
template<bool GATHER>
__device__ __forceinline__ void run_phase_f(
    f32x16 (&acc)[4],
    const float* __restrict__ aF,
    const uint16_t* __restrict__ aHi, const uint16_t* __restrict__ aLo,
    const int* __restrict__ ridx, int rstride,
    const float* __restrict__ W, int K, bool gateRe,
    int jb, int w, int lrow, int lgrp)
{
  const int nFS = K >> 7;
  const int wrow = gateRe ? ((lrow >> 3) * H_ + jb * 8 + (lrow & 7))
                          : (jb * 32 + lrow);
  const float* bptr = W + (size_t)wrow * K + lgrp * 8;

  size_t aoff0, aoff1, aoff2, aoff3;
  if (GATHER) {
    aoff0 = (size_t)ridx[(size_t)(lrow)      * rstride] * E_ + lgrp * 8;
    aoff1 = (size_t)ridx[(size_t)(32 + lrow) * rstride] * E_ + lgrp * 8;
    aoff2 = (size_t)ridx[(size_t)(64 + lrow) * rstride] * E_ + lgrp * 8;
    aoff3 = (size_t)ridx[(size_t)(96 + lrow) * rstride] * E_ + lgrp * 8;
  } else {
    aoff0 = (size_t)lgrp * 256 + (size_t)lrow * 8;
    aoff1 = aoff0 + 512;
    aoff2 = aoff0 + 1024;
    aoff3 = aoff0 + 1536;
  }

  float4 bR0[2], bR1[2];
  float4 gR0[2][2], gR1[2][2], gR2[2][2], gR3[2][2];
  bf16x8 sh0[2], sh1[2], sh2[2], sh3[2], sl0[2], sl1[2], sl2[2], sl3[2];

#define LOADFS(BUF, KS)                                                      \
  {                                                                          \
    const float* bp = bptr + (size_t)(KS) * 16;                              \
    bR0[BUF] = ((const float4*)bp)[0];                                       \
    bR1[BUF] = ((const float4*)bp)[1];                                       \
    if (GATHER) {                                                            \
      const float* a0 = aF + aoff0 + (size_t)(KS) * 16;                      \
      const float* a1 = aF + aoff1 + (size_t)(KS) * 16;                      \
      const float* a2 = aF + aoff2 + (size_t)(KS) * 16;                      \
      const float* a3 = aF + aoff3 + (size_t)(KS) * 16;                      \
      gR0[BUF][0] = ((const float4*)a0)[0]; gR0[BUF][1] = ((const float4*)a0)[1]; \
      gR1[BUF][0] = ((const float4*)a1)[0]; gR1[BUF][1] = ((const float4*)a1)[1]; \
      gR2[BUF][0] = ((const float4*)a2)[0]; gR2[BUF][1] = ((const float4*)a2)[1]; \
      gR3[BUF][0] = ((const float4*)a3)[0]; gR3[BUF][1] = ((const float4*)a3)[1]; \
    } else {                                                                 \
      size_t o0 = aoff0 + (size_t)(KS) * 2048;                               \
      size_t o1 = aoff1 + (size_t)(KS) * 2048;                               \
      size_t o2 = aoff2 + (size_t)(KS) * 2048;                               \
      size_t o3 = aoff3 + (size_t)(KS) * 2048;                               \
      sh0[BUF] = *(const bf16x8*)(aHi + o0); sl0[BUF] = *(const bf16x8*)(aLo + o0); \
      sh1[BUF] = *(const bf16x8*)(aHi + o1); sl1[BUF] = *(const bf16x8*)(aLo + o1); \
      sh2[BUF] = *(const bf16x8*)(aHi + o2); sl2[BUF] = *(const bf16x8*)(aLo + o2); \
      sh3[BUF] = *(const bf16x8*)(aHi + o3); sl3[BUF] = *(const bf16x8*)(aLo + o3); \
    }                                                                        \
  }

#define COMPFS(BUF)                                                          \
  {                                                                          \
    bf16x8 bh, bl;                                                           \
    splitpack(bR0[BUF], bR1[BUF], bh, bl);                                   \
    bf16x8 ah, al;                                                           \
    if (GATHER) splitpack(gR0[BUF][0], gR0[BUF][1], ah, al);                 \
    else { ah = sh0[BUF]; al = sl0[BUF]; }                                   \
    acc[0] = MFMA_(ah, bh, acc[0]);                                          \
    acc[0] = MFMA_(ah, bl, acc[0]);                                          \
    acc[0] = MFMA_(al, bh, acc[0]);                                          \
    if (GATHER) splitpack(gR1[BUF][0], gR1[BUF][1], ah, al);                 \
    else { ah = sh1[BUF]; al = sl1[BUF]; }                                   \
    acc[1] = MFMA_(ah, bh, acc[1]);                                          \
    acc[1] = MFMA_(ah, bl, acc[1]);                                          \
    acc[1] = MFMA_(al, bh, acc[1]);                                          \
    if (GATHER) splitpack(gR2[BUF][0], gR2[BUF][1], ah, al);                 \
    else { ah = sh2[BUF]; al = sl2[BUF]; }                                   \
    acc[2] = MFMA_(ah, bh, acc[2]);                                          \
    acc[2] = MFMA_(ah, bl, acc[2]);                                          \
    acc[2] = MFMA_(al, bh, acc[2]);                                          \
    if (GATHER) splitpack(gR3[BUF][0], gR3[BUF][1], ah, al);                 \
    else { ah = sh3[BUF]; al = sl3[BUF]; }                                   \
    acc[3] = MFMA_(ah, bh, acc[3]);                                          \
    acc[3] = MFMA_(ah, bl, acc[3]);                                          \
    acc[3] = MFMA_(al, bh, acc[3]);                                          \
  }

  int ks = w;
  LOADFS(0, ks); ks += 8;
  int rem = nFS;
  while (rem >= 2) {
    LOADFS(1, ks); ks += 8;
    COMPFS(0);
    if (rem > 2) { LOADFS(0, ks); ks += 8; }
    COMPFS(1);
    rem -= 2;
  }
#undef LOADFS
#undef COMPFS
}

template<int EPI, int GATHER1>
__global__ __launch_bounds__(512, 2) void gemm_ks_f(
    const float* __restrict__ a1F,
    const uint16_t* __restrict__ a1Hi, const uint16_t* __restrict__ a1Lo,
    const int* __restrict__ ridx, int rstride,
    const float* __restrict__ W1, int K1,
    const uint16_t* __restrict__ a2Hi, const uint16_t* __restrict__ a2Lo,
    const float* __restrict__ W2, int K2,
    const float* __restrict__ bih, const float* __restrict__ bhh,
    float* __restrict__ cState,
    uint16_t* __restrict__ hOutHi, uint16_t* __restrict__ hOutLo,
    const float* __restrict__ bias, float* __restrict__ Cout)
{
  __shared__ float red[4][128 * 32];

  const int jb   = blockIdx.x;
  const int tid  = threadIdx.x;
  const int w    = tid >> 6;
  const int lane = tid & 63;
  const int lrow = lane & 31;
  const int lgrp = lane >> 5;

  f32x16 acc[4];
#pragma unroll
  for (int mf = 0; mf < 4; ++mf)
#pragma unroll
    for (int r = 0; r < 16; ++r) acc[mf][r] = 0.0f;

  run_phase_f<GATHER1 != 0>(acc, a1F, a1Hi, a1Lo, ridx, rstride,
                            W1, K1, EPI == 1, jb, w, lrow, lgrp);
  if (K2 > 0)
    run_phase_f<false>(acc, nullptr, a2Hi, a2Lo, nullptr, 0,
                       W2, K2, EPI == 1, jb, w, lrow, lgrp);

  const int wl = w & 3;
  if (w < 4) {
#pragma unroll
    for (int mf = 0; mf < 4; ++mf)
#pragma unroll
      for (int r = 0; r < 16; ++r) {
        const int row = mf * 32 + (r & 3) + 8 * (r >> 2) + 4 * lgrp;
        red[wl][row * 32 + (lrow ^ (row & 31))] = acc[mf][r];
      }
  }
  __syncthreads();
  if (w >= 4) {
#pragma unroll
    for (int mf = 0; mf < 4; ++mf)
#pragma unroll
      for (int r = 0; r < 16; ++r) {
        const int row = mf * 32 + (r & 3) + 8 * (r >> 2) + 4 * lgrp;
        red[wl][row * 32 + (lrow ^ (row & 31))] += acc[mf][r];
      }
  }
  __syncthreads();

  if constexpr (EPI == 1) {
    const int b  = tid & 127;
    const int uh = (tid >> 7) * 2;
#pragma unroll
    for (int q = 0; q < 2; ++q) {
      const int u = uh + q;
      float gs[4];
#pragma unroll
      for (int g = 0; g < 4; ++g) {
        const int cs = (g * 8 + u) ^ (b & 31);
        gs[g] = ((red[0][b * 32 + cs] + red[1][b * 32 + cs])
                 + red[2][b * 32 + cs]) + red[3][b * 32 + cs];
      }
      const int n = jb * 8 + u;
      float gi = gs[0] + bih[n]          + bhh[n];
      float gf = gs[1] + bih[H_ + n]     + bhh[H_ + n];
      float gg = gs[2] + bih[2 * H_ + n] + bhh[2 * H_ + n];
      float go = gs[3] + bih[3 * H_ + n] + bhh[3 * H_ + n];
      float si = 1.f / (1.f + expf(-gi));
      float sf = 1.f / (1.f + expf(-gf));
      float so = 1.f / (1.f + expf(-go));
      const size_t ci = (size_t)b * H_ + n;
      float cv = sf * cState[ci] + si * tanhf(gg);
      cState[ci] = cv;
      float hv = so * tanhf(cv);
      uint16_t hh, hl;
      split2(hv, hh, hl);
      const size_t hoff = (size_t)((n >> 4) * 4 + (b >> 5)) * 512
                        + (size_t)((n >> 3) & 1) * 256
                        + (size_t)(b & 31) * 8 + (size_t)(n & 7);
      hOutHi[hoff] = hh;
      hOutLo[hoff] = hl;
    }
  } else {
    const int b  = tid & 127;
    const int ch = (tid >> 7) * 8;
#pragma unroll
    for (int q = 0; q < 8; ++q) {
      const int col = ch + q;
      const int cs  = col ^ (b & 31);
      float v = ((red[0][b * 32 + cs] + red[1][b * 32 + cs])
                 + red[2][b * 32 + cs]) + red[3][b * 32 + cs];
      Cout[(size_t)b * V_ + jb * 32 + col] = v + bias[jb * 32 + col];
    }
  }
}

// ---------------------------------------------------------------------------
// categorical sampling (verbatim from passing rounds 3-7,10)
// ---------------------------------------------------------------------------
__global__ __launch_bounds__(256) void sample_kernel(
    const float* __restrict__ logits, const uint32_t* __restrict__ keys,
    int t, int* __restrict__ out, int col)
{
  const int b = blockIdx.x;
  const int tid = threadIdx.x;
  const uint32_t k0 = keys[2 * t];
  const uint32_t k1 = keys[2 * t + 1];
  const float* lrow = logits + (size_t)b * V_;

  float best = -3.4e38f;
  int bestIdx = 0;
  for (int v = tid; v < V_; v += 256) {
    uint32_t j = (uint32_t)(b * V_ + v);
    uint32_t o0, o1;
    threefry2x32(k0, k1, 0u, j, o0, o1);
    uint32_t bits = o0 ^ o1;
    float f = __uint_as_float((bits >> 9) | 0x3f800000u) - 1.0f;
    float u = fmaxf(1.17549435e-38f, f + 1.17549435e-38f);
    float t1 = (float)log((double)u);
    float t2 = -t1;
    float t3 = (float)log((double)t2);
    float val = (-t3) + lrow[v];
    if (val > best) { best = val; bestIdx = v; }
  }

  __shared__ float sv[256];
  __shared__ int   si[256];
  sv[tid] = best; si[tid] = bestIdx;
  __syncthreads();
  for (int s = 128; s > 0; s >>= 1) {
    if (tid < s) {
      float v2 = sv[tid + s]; int i2 = si[tid + s];
      if (v2 > sv[tid] || (v2 == sv[tid] && i2 < si[tid])) { sv[tid] = v2; si[tid] = i2; }
    }
    __syncthreads();
  }
  if (tid == 0) out[b * S_ + col] = si[0];
}

// ---------------------------------------------------------------------------
extern "C" void kernel_launch(void* const* d_in, const int* in_sizes, int n_in,
                              void* d_out, int out_size, void* d_ws, size_t ws_size,
                              hipStream_t stream) {
  const int*   x    = (const int*)  d_in[0];
  const float* emb  = (const float*)d_in[3];
  const float* Wih0 = (const float*)d_in[4];
  const float* Whh0 = (const float*)d_in[5];
  const float* bih0 = (const float*)d_in[6];
  const float* bhh0 = (const float*)d_in[7];
  const float* Wih1 = (const float*)d_in[8];
  const float* Whh1 = (const float*)d_in[9];
  const float* bih1 = (const float*)d_in[10];
  const float* bhh1 = (const float*)d_in[11];
  const float* Wlin = (const float*)d_in[12];
  const float* blin = (const float*)d_in[13];
  int* out = (int*)d_out;

  // ---- workspace carve-up ----
  char* wp = (char*)d_ws;
  size_t o = 0;
  auto alloc = [&](size_t bytes) {
    void* p = wp + o; o += (bytes + 255) & ~(size_t)255; return p;
  };
  uint32_t* keys   = (uint32_t*)alloc(512);
  float*    logits = (float*)   alloc((size_t)B_ * V_ * 4);
  float*    c0     = (float*)   alloc((size_t)B_ * H_ * 4);   // zero-block start
  float*    c1     = (float*)   alloc((size_t)B_ * H_ * 4);
  uint16_t* hS0hi[2]; uint16_t* hS0lo[2]; uint16_t* hS1hi[2]; uint16_t* hS1lo[2];
  for (int i = 0; i < 2; ++i) hS0hi[i] = (uint16_t*)alloc((size_t)B_ * H_ * 2);
  for (int i = 0; i < 2; ++i) hS0lo[i] = (uint16_t*)alloc((size_t)B_ * H_ * 2);
  for (int i = 0; i < 2; ++i) hS1hi[i] = (uint16_t*)alloc((size_t)B_ * H_ * 2);
  for (int i = 0; i < 2; ++i) hS1lo[i] = (uint16_t*)alloc((size_t)B_ * H_ * 2);
  size_t zeroBytes = (size_t)((char*)hS1lo[1] + (size_t)B_ * H_ * 2 - (char*)c0);

  // panel allocations (only valid if ws_size allows)
  const size_t nIh0 = (size_t)H4_ * E_;    // 4.19M
  const size_t nHh  = (size_t)H4_ * H_;    // 16.78M (x3)
  const size_t nLin = (size_t)V_ * H_;     // 16.38M
  uint16_t* PHih0 = (uint16_t*)alloc(nIh0 * 2);
  uint8_t*  PMih0 = (uint8_t*) alloc(nIh0);
  uint16_t* PHhh0 = (uint16_t*)alloc(nHh * 2);
  uint8_t*  PMhh0 = (uint8_t*) alloc(nHh);
  uint16_t* PHih1 = (uint16_t*)alloc(nHh * 2);
  uint8_t*  PMih1 = (uint8_t*) alloc(nHh);
  uint16_t* PHhh1 = (uint16_t*)alloc(nHh * 2);
  uint8_t*  PMhh1 = (uint8_t*) alloc(nHh);
  uint16_t* PHlin = (uint16_t*)alloc(nLin * 2);
  uint8_t*  PMlin = (uint8_t*) alloc(nLin);
  const bool usePacked = (o <= ws_size);

  hipMemsetAsync(c0, 0, zeroBytes, stream);
  keys_kernel<<<1, 64, 0, stream>>>(keys);
  copy_prefix<<<(B_ * GIVEN_) / 256, 256, 0, stream>>>(x, out);

  if (usePacked) {
    pack3<<<(int)((nIh0 / 8 + 255) / 256), 256, 0, stream>>>(Wih0, PHih0, PMih0, (int)(nIh0 / 8));
    pack3<<<(int)((nHh / 8 + 255) / 256), 256, 0, stream>>>(Whh0, PHhh0, PMhh0, (int)(nHh / 8));
    pack3<<<(int)((nHh / 8 + 255) / 256), 256, 0, stream>>>(Wih1, PHih1, PMih1, (int)(nHh / 8));
    pack3<<<(int)((nHh / 8 + 255) / 256), 256, 0, stream>>>(Whh1, PHhh1, PMhh1, (int)(nHh / 8));
    pack3<<<(int)((nLin / 8 + 255) / 256), 256, 0, stream>>>(Wlin, PHlin, PMlin, (int)(nLin / 8));
  }

  int p = 0;
  auto lstm_step = [&](const int* ridx) {
    if (usePacked) {
      gemm_ks_p<1, 1><<<H_ / 8, 512, 0, stream>>>(
          emb, nullptr, nullptr, ridx, S_, PHih0, PMih0, E_,
          hS0hi[p], hS0lo[p], PHhh0, PMhh0, H_,
          bih0, bhh0, c0, hS0hi[p ^ 1], hS0lo[p ^ 1], nullptr, nullptr);
      gemm_ks_p<1, 0><<<H_ / 8, 512, 0, stream>>>(
          nullptr, hS0hi[p ^ 1], hS0lo[p ^ 1], nullptr, 0, PHih1, PMih1, H_,
          hS1hi[p], hS1lo[p], PHhh1, PMhh1, H_,
          bih1, bhh1, c1, hS1hi[p ^ 1], hS1lo[p ^ 1], nullptr, nullptr);
    } else {
      gemm_ks_f<1, 1><<<H_ / 8, 512, 0, stream>>>(
          emb, nullptr, nullptr, ridx, S_, Wih0, E_,
          hS0hi[p], hS0lo[p], Whh0, H_,
          bih0, bhh0, c0, hS0hi[p ^ 1], hS0lo[p ^ 1], nullptr, nullptr);
      gemm_ks_f<1, 0><<<H_ / 8, 512, 0, stream>>>(
          nullptr, hS0hi[p ^ 1], hS0lo[p ^ 1], nullptr, 0, Wih1, H_,
          hS1hi[p], hS1lo[p], Whh1, H_,
          bih1, bhh1, c1, hS1hi[p ^ 1], hS1lo[p ^ 1], nullptr, nullptr);
    }
    p ^= 1;
  };

  // teacher forcing
  for (int t = 0; t < GIVEN_; ++t) {
    lstm_step(x + t);
  }

  // rollout
  for (int t = 0; t < S_ - GIVEN_; ++t) {
    const int* ridx = (t == 0) ? (x + (GIVEN_ - 1)) : (out + (GIVEN_ + t - 1));
    lstm_step(ridx);
    if (usePacked) {
      gemm_ks_p<0, 0><<<V_ / 32, 512, 0, stream>>>(
          nullptr, hS1hi[p], hS1lo[p], nullptr, 0, PHlin, PMlin, H_,
          nullptr, nullptr, nullptr, nullptr, 0,
          nullptr, nullptr, nullptr, nullptr, nullptr, blin, logits);
    } else {
      gemm_ks_f<0, 0><<<V_ / 32, 512, 0, stream>>>(
          nullptr, hS1hi[p], hS1lo[p], nullptr, 0, Wlin, H_,
          nullptr, nullptr, nullptr, 0,
          nullptr, nullptr, nullptr, nullptr, nullptr, blin, logits);
    }
    sample_kernel<<<B_, 256, 0, stream>>>(logits, keys, t, out, GIVEN_ + t);
  }
}

// Round 13
// 10974.265 us; speedup vs baseline: 1.2795x; 1.2087x over previous
//
#include <hip/hip_runtime.h>
#include <stdint.h>
#include <math.h>

// Problem constants (fixed by setup_inputs)
#define B_     128
#define S_     128
#define V_     8000
#define E_     512
#define H_     2048
#define H4_    8192
#define GIVEN_ 64

typedef __bf16 bf16x8 __attribute__((ext_vector_type(8)));
typedef float  f32x16 __attribute__((ext_vector_type(16)));
typedef short  short8 __attribute__((ext_vector_type(8)));

// ---------------------------------------------------------------------------
// Threefry-2x32 (20 rounds) — exact JAX semantics (verified passing r3-r7,r10)
// ---------------------------------------------------------------------------
__device__ __forceinline__ uint32_t rotl32(uint32_t v, int d) {
  return (v << d) | (v >> (32 - d));
}

__device__ __forceinline__ void threefry2x32(uint32_t k0, uint32_t k1,
                                             uint32_t x0, uint32_t x1,
                                             uint32_t& o0, uint32_t& o1) {
  uint32_t k2 = k0 ^ k1 ^ 0x1BD11BDAu;
  x0 += k0; x1 += k1;
#define TF_RND(R) { x0 += x1; x1 = rotl32(x1, (R)); x1 ^= x0; }
  TF_RND(13) TF_RND(15) TF_RND(26) TF_RND(6)
  x0 += k1; x1 += k2 + 1u;
  TF_RND(17) TF_RND(29) TF_RND(16) TF_RND(24)
  x0 += k2; x1 += k0 + 2u;
  TF_RND(13) TF_RND(15) TF_RND(26) TF_RND(6)
  x0 += k0; x1 += k1 + 3u;
  TF_RND(17) TF_RND(29) TF_RND(16) TF_RND(24)
  x0 += k1; x1 += k2 + 4u;
  TF_RND(13) TF_RND(15) TF_RND(26) TF_RND(6)
  x0 += k2; x1 += k0 + 5u;
#undef TF_RND
  o0 = x0; o1 = x1;
}

__global__ void keys_kernel(uint32_t* __restrict__ keys) {
  int t = threadIdx.x;  // 0..63
  uint32_t o0, o1;
  threefry2x32(0u, 1u, 0u, (uint32_t)t, o0, o1);
  keys[2 * t]     = o0;
  keys[2 * t + 1] = o1;
}

__global__ void copy_prefix(const int* __restrict__ x, int* __restrict__ out) {
  int idx = blockIdx.x * blockDim.x + threadIdx.x;
  int b = idx >> 6;
  int s = idx & 63;
  out[b * S_ + s] = x[b * S_ + s];
}

// split f32 -> hi/lo bf16 (truncation; identical math to passing rounds)
__device__ __forceinline__ void split2(float x, uint16_t& hi, uint16_t& lo) {
  uint32_t xb = __float_as_uint(x);
  hi = (uint16_t)(xb >> 16);
  float l = x - __uint_as_float(xb & 0xFFFF0000u);
  lo = (uint16_t)(__float_as_uint(l) >> 16);
}

__device__ __forceinline__ void splitpack(float4 a, float4 b,
                                          bf16x8& hi, bf16x8& lo) {
  float e[8] = {a.x, a.y, a.z, a.w, b.x, b.y, b.z, b.w};
  short8 h, l;
#pragma unroll
  for (int j = 0; j < 8; ++j) {
    uint16_t h16, l16;
    split2(e[j], h16, l16);
    h[j] = (short)h16;
    l[j] = (short)l16;
  }
  hi = __builtin_bit_cast(bf16x8, h);
  lo = __builtin_bit_cast(bf16x8, l);
}

// unpack packed-3B weight frag: hi bf16x8 (direct) + 8 mid-bytes -> lo bf16x8
__device__ __forceinline__ void unpack3(short8 hv, uint2 m, bf16x8& bh, bf16x8& bl) {
  short8 lv;
#pragma unroll
  for (int j = 0; j < 8; ++j) {
    uint32_t hbits = ((uint32_t)(uint16_t)hv[j]) << 16;
    uint32_t mbyte = ((j < 4 ? (m.x >> (8 * j)) : (m.y >> (8 * (j - 4)))) & 0xFFu);
    float xf = __uint_as_float(hbits | (mbyte << 8));
    float lf = xf - __uint_as_float(hbits);
    lv[j] = (short)(__float_as_uint(lf) >> 16);
  }
  bh = __builtin_bit_cast(bf16x8, hv);
  bl = __builtin_bit_cast(bf16x8, lv);
}

// ---------------------------------------------------------------------------
// Panel packer: W (N x K f32, row-major) -> PH/PM in MFMA FRAGMENT ORDER.
// Fragment (jb, ks) = the 32 rows x 16 k-elems one wave consumes per k-step.
// Lane l = lgrp*32+lrow reads elems [lgrp*8..+8) of row wrow(lrow, jb).
// Layout: elem index  bi = ((jb*nks + ks)*64 + l)*8  (PH: uint16, PM: byte)
//   -> a wave's per-k-step B load is contiguous 1KB (PH) + 512B (PM).
// gateRe: block jb covers hidden units jb*8..+7, cols = gate*8 + unit.
// ---------------------------------------------------------------------------
__global__ void pack3_panel(
    const float* __restrict__ W, uint16_t* __restrict__ PH,
    uint8_t* __restrict__ PM, int K, int nks, int gateRe)
{
  const int bid = blockIdx.x;
  const int jb = bid / nks, ks = bid - jb * nks;
  const int t = threadIdx.x;     // 0..63
  const int lrow = t & 31, lgrp = t >> 5;
  const int wrow = gateRe ? ((lrow >> 3) * H_ + jb * 8 + (lrow & 7))
                          : (jb * 32 + lrow);
  const float* src = W + (size_t)wrow * K + ks * 16 + lgrp * 8;
  float4 a = ((const float4*)src)[0];
  float4 b = ((const float4*)src)[1];
  float e[8] = {a.x, a.y, a.z, a.w, b.x, b.y, b.z, b.w};
  short8 h;
  uint32_t mlo = 0, mhi = 0;
#pragma unroll
  for (int j = 0; j < 8; ++j) {
    uint32_t xb = __float_as_uint(e[j]);
    h[j] = (short)(xb >> 16);
    uint32_t mb = (xb >> 8) & 0xFFu;
    if (j < 4) mlo |= mb << (8 * j);
    else       mhi |= mb << (8 * (j - 4));
  }
  const size_t bi = ((size_t)bid * 64 + t) * 8;
  *(short8*)&PH[bi] = h;
  *(uint2*)&PM[bi] = make_uint2(mlo, mhi);
}

#define MFMA_(a, b, c) __builtin_amdgcn_mfma_f32_32x32x16_bf16(a, b, c, 0, 0, 0)

// ===========================================================================
// PACKED-PANEL GEMM phase (r10 geometry/loop: M=128 x N=32, 2-deep dbuf):
// acc[4] += A(128 x K) @ W^T for this block's 32 output cols.
// B from fragment-ordered PH/PM panels -> per-k-step load is CONTIGUOUS
// 1KB+512B per wave (24B/lane). A gathered-f32 (emb) or pre-split staged-h.
// 8 waves K-split: wave w takes k16-steps w, w+8, ...
// staged-h layout: elem(b,n) at ((n>>4)*4+(b>>5))*512+((n>>3)&1)*256+(b&31)*8+(n&7)
// ===========================================================================
template<bool GATHER>
__device__ __forceinline__ void run_phase_p(
    f32x16 (&acc)[4],
    const float* __restrict__ aF,
    const uint16_t* __restrict__ aHi, const uint16_t* __restrict__ aLo,
    const int* __restrict__ ridx, int rstride,
    const uint16_t* __restrict__ PH, const uint8_t* __restrict__ PM,
    int K, int jb, int w, int lane, int lrow, int lgrp)
{
  const int nFS = K >> 7;               // k16-steps per wave (4 or 16)
  const size_t bbase = (size_t)jb * (K >> 4);

  size_t aoff0, aoff1, aoff2, aoff3;
  if (GATHER) {
    aoff0 = (size_t)ridx[(size_t)(lrow)      * rstride] * E_ + lgrp * 8;
    aoff1 = (size_t)ridx[(size_t)(32 + lrow) * rstride] * E_ + lgrp * 8;
    aoff2 = (size_t)ridx[(size_t)(64 + lrow) * rstride] * E_ + lgrp * 8;
    aoff3 = (size_t)ridx[(size_t)(96 + lrow) * rstride] * E_ + lgrp * 8;
  } else {
    aoff0 = (size_t)lgrp * 256 + (size_t)lrow * 8;
    aoff1 = aoff0 + 512;
    aoff2 = aoff0 + 1024;
    aoff3 = aoff0 + 1536;
  }

  short8 bH[2]; uint2 bM[2];
  float4 gR0[2][2], gR1[2][2], gR2[2][2], gR3[2][2];
  bf16x8 sh0[2], sh1[2], sh2[2], sh3[2], sl0[2], sl1[2], sl2[2], sl3[2];

#define LOADFS(BUF, KS)                                                      \
  {                                                                          \
    const size_t bi = ((bbase + (size_t)(KS)) * 64 + (size_t)lane) * 8;      \
    bH[BUF] = *(const short8*)(PH + bi);                                     \
    bM[BUF] = *(const uint2*)(PM + bi);                                      \
    if (GATHER) {                                                            \
      const float* a0 = aF + aoff0 + (size_t)(KS) * 16;                      \
      const float* a1 = aF + aoff1 + (size_t)(KS) * 16;                      \
      const float* a2 = aF + aoff2 + (size_t)(KS) * 16;                      \
      const float* a3 = aF + aoff3 + (size_t)(KS) * 16;                      \
      gR0[BUF][0] = ((const float4*)a0)[0]; gR0[BUF][1] = ((const float4*)a0)[1]; \
      gR1[BUF][0] = ((const float4*)a1)[0]; gR1[BUF][1] = ((const float4*)a1)[1]; \
      gR2[BUF][0] = ((const float4*)a2)[0]; gR2[BUF][1] = ((const float4*)a2)[1]; \
      gR3[BUF][0] = ((const float4*)a3)[0]; gR3[BUF][1] = ((const float4*)a3)[1]; \
    } else {                                                                 \
      size_t o0 = aoff0 + (size_t)(KS) * 2048;                               \
      size_t o1 = aoff1 + (size_t)(KS) * 2048;                               \
      size_t o2 = aoff2 + (size_t)(KS) * 2048;                               \
      size_t o3 = aoff3 + (size_t)(KS) * 2048;                               \
      sh0[BUF] = *(const bf16x8*)(aHi + o0); sl0[BUF] = *(const bf16x8*)(aLo + o0); \
      sh1[BUF] = *(const bf16x8*)(aHi + o1); sl1[BUF] = *(const bf16x8*)(aLo + o1); \
      sh2[BUF] = *(const bf16x8*)(aHi + o2); sl2[BUF] = *(const bf16x8*)(aLo + o2); \
      sh3[BUF] = *(const bf16x8*)(aHi + o3); sl3[BUF] = *(const bf16x8*)(aLo + o3); \
    }                                                                        \
  }

#define COMPFS(BUF)                                                          \
  {                                                                          \
    bf16x8 bh, bl;                                                           \
    unpack3(bH[BUF], bM[BUF], bh, bl);                                       \
    bf16x8 ah, al;                                                           \
    if (GATHER) splitpack(gR0[BUF][0], gR0[BUF][1], ah, al);                 \
    else { ah = sh0[BUF]; al = sl0[BUF]; }                                   \
    acc[0] = MFMA_(ah, bh, acc[0]);                                          \
    acc[0] = MFMA_(ah, bl, acc[0]);                                          \
    acc[0] = MFMA_(al, bh, acc[0]);                                          \
    if (GATHER) splitpack(gR1[BUF][0], gR1[BUF][1], ah, al);                 \
    else { ah = sh1[BUF]; al = sl1[BUF]; }                                   \
    acc[1] = MFMA_(ah, bh, acc[1]);                                          \
    acc[1] = MFMA_(ah, bl, acc[1]);                                          \
    acc[1] = MFMA_(al, bh, acc[1]);                                          \
    if (GATHER) splitpack(gR2[BUF][0], gR2[BUF][1], ah, al);                 \
    else { ah = sh2[BUF]; al = sl2[BUF]; }                                   \
    acc[2] = MFMA_(ah, bh, acc[2]);                                          \
    acc[2] = MFMA_(ah, bl, acc[2]);                                          \
    acc[2] = MFMA_(al, bh, acc[2]);                                          \
    if (GATHER) splitpack(gR3[BUF][0], gR3[BUF][1], ah, al);                 \
    else { ah = sh3[BUF]; al = sl3[BUF]; }                                   \
    acc[3] = MFMA_(ah, bh, acc[3]);                                          \
    acc[3] = MFMA_(ah, bl, acc[3]);                                          \
    acc[3] = MFMA_(al, bh, acc[3]);                                          \
  }

  int ks = w;
  LOADFS(0, ks); ks += 8;
  int rem = nFS;              // even: 4 or 16
  while (rem >= 2) {
    LOADFS(1, ks); ks += 8;
    COMPFS(0);
    if (rem > 2) { LOADFS(0, ks); ks += 8; }
    COMPFS(1);
    rem -= 2;
  }
#undef LOADFS
#undef COMPFS
}

// ---------------------------------------------------------------------------
// Fused dual-GEMM + epilogue (r10 structure, panel-B). M=128 x N=32 tile.
// ---------------------------------------------------------------------------
template<int EPI, int GATHER1>
__global__ __launch_bounds__(512, 2) void gemm_ks_p(
    const float* __restrict__ a1F,
    const uint16_t* __restrict__ a1Hi, const uint16_t* __restrict__ a1Lo,
    const int* __restrict__ ridx, int rstride,
    const uint16_t* __restrict__ PH1, const uint8_t* __restrict__ PM1, int K1,
    const uint16_t* __restrict__ a2Hi, const uint16_t* __restrict__ a2Lo,
    const uint16_t* __restrict__ PH2, const uint8_t* __restrict__ PM2, int K2,
    const float* __restrict__ bih, const float* __restrict__ bhh,
    float* __restrict__ cState,
    uint16_t* __restrict__ hOutHi, uint16_t* __restrict__ hOutLo,
    const float* __restrict__ bias, float* __restrict__ Cout)
{
  __shared__ float red[4][128 * 32];   // 64 KiB

  const int jb   = blockIdx.x;
  const int tid  = threadIdx.x;
  const int w    = tid >> 6;
  const int lane = tid & 63;
  const int lrow = lane & 31;
  const int lgrp = lane >> 5;

  f32x16 acc[4];
#pragma unroll
  for (int mf = 0; mf < 4; ++mf)
#pragma unroll
    for (int r = 0; r < 16; ++r) acc[mf][r] = 0.0f;

  run_phase_p<GATHER1 != 0>(acc, a1F, a1Hi, a1Lo, ridx, rstride,
                            PH1, PM1, K1, jb, w, lane, lrow, lgrp);
  if (K2 > 0)
    run_phase_p<false>(acc, nullptr, a2Hi, a2Lo, nullptr, 0,
                       PH2, PM2, K2, jb, w, lane, lrow, lgrp);

  const int wl = w & 3;
  if (w < 4) {
#pragma unroll
    for (int mf = 0; mf < 4; ++mf)
#pragma unroll
      for (int r = 0; r < 16; ++r) {
        const int row = mf * 32 + (r & 3) + 8 * (r >> 2) + 4 * lgrp;
        red[wl][row * 32 + (lrow ^ (row & 31))] = acc[mf][r];
      }
  }
  __syncthreads();
  if (w >= 4) {
#pragma unroll
    for (int mf = 0; mf < 4; ++mf)
#pragma unroll
      for (int r = 0; r < 16; ++r) {
        const int row = mf * 32 + (r & 3) + 8 * (r >> 2) + 4 * lgrp;
        red[wl][row * 32 + (lrow ^ (row & 31))] += acc[mf][r];
      }
  }
  __syncthreads();

  if constexpr (EPI == 1) {
    const int b  = tid & 127;
    const int uh = (tid >> 7) * 2;   // 0,2,4,6
#pragma unroll
    for (int q = 0; q < 2; ++q) {
      const int u = uh + q;
      float gs[4];
#pragma unroll
      for (int g = 0; g < 4; ++g) {
        const int cs = (g * 8 + u) ^ (b & 31);
        gs[g] = ((red[0][b * 32 + cs] + red[1][b * 32 + cs])
                 + red[2][b * 32 + cs]) + red[3][b * 32 + cs];
      }
      const int n = jb * 8 + u;
      float gi = gs[0] + bih[n]          + bhh[n];
      float gf = gs[1] + bih[H_ + n]     + bhh[H_ + n];
      float gg = gs[2] + bih[2 * H_ + n] + bhh[2 * H_ + n];
      float go = gs[3] + bih[3 * H_ + n] + bhh[3 * H_ + n];
      float si = 1.f / (1.f + expf(-gi));
      float sf = 1.f / (1.f + expf(-gf));
      float so = 1.f / (1.f + expf(-go));
      const size_t ci = (size_t)b * H_ + n;
      float cv = sf * cState[ci] + si * tanhf(gg);
      cState[ci] = cv;
      float hv = so * tanhf(cv);
      uint16_t hh, hl;
      split2(hv, hh, hl);
      const size_t hoff = (size_t)((n >> 4) * 4 + (b >> 5)) * 512
                        + (size_t)((n >> 3) & 1) * 256
                        + (size_t)(b & 31) * 8 + (size_t)(n & 7);
      hOutHi[hoff] = hh;
      hOutLo[hoff] = hl;
    }
  } else {
    const int b  = tid & 127;
    const int ch = (tid >> 7) * 8;
#pragma unroll
    for (int q = 0; q < 8; ++q) {
      const int col = ch + q;
      const int cs  = col ^ (b & 31);
      float v = ((red[0][b * 32 + cs] + red[1][b * 32 + cs])
                 + red[2][b * 32 + cs]) + red[3][b * 32 + cs];
      Cout[(size_t)b * V_ + jb * 32 + col] = v + bias[jb * 32 + col];
    }
  }
}

// ===========================================================================
// FALLBACK: r7 f32-B GEMM, N=32 tile, verbatim (only if ws can't hold panels).
// ===========================================================================
template<bool GATHER>
__device__ __forceinline__ void run_phase_f(
    f32x16 (&acc)[4],
    const float* __restrict__ aF,
    const uint16_t* __restrict__ aHi, const uint16_t* __restrict__ aLo,
    const int* __restrict__ ridx, int rstride,
    const float* __restrict__ W, int K, bool gateRe,
    int jb, int w, int lrow, int lgrp)
{
  const int nFS = K >> 7;
  const int wrow = gateRe ? ((lrow >> 3) * H_ + jb * 8 + (lrow & 7))
                          : (jb * 32 + lrow);
  const float* bptr = W + (size_t)wrow * K + lgrp * 8;

  size_t aoff0, aoff1, aoff2, aoff3;
  if (GATHER) {
    aoff0 = (size_t)ridx[(size_t)(lrow)      * rstride] * E_ + lgrp * 8;
    aoff1 = (size_t)ridx[(size_t)(32 + lrow) * rstride] * E_ + lgrp * 8;
    aoff2 = (size_t)ridx[(size_t)(64 + lrow) * rstride] * E_ + lgrp * 8;
    aoff3 = (size_t)ridx[(size_t)(96 + lrow) * rstride] * E_ + lgrp * 8;
  } else {
    aoff0 = (size_t)lgrp * 256 + (size_t)lrow * 8;
    aoff1 = aoff0 + 512;
    aoff2 = aoff0 + 1024;
    aoff3 = aoff0 + 1536;
  }

  float4 bR0[2], bR1[2];
  float4 gR0[2][2], gR1[2][2], gR2[2][2], gR3[2][2];
  bf16x8 sh0[2], sh1[2], sh2[2], sh3[2], sl0[2], sl1[2], sl2[2], sl3[2];

#define LOADFS(BUF, KS)                                                      \
  {                                                                          \
    const float* bp = bptr + (size_t)(KS) * 16;                              \
    bR0[BUF] = ((const float4*)bp)[0];                                       \
    bR1[BUF] = ((const float4*)bp)[1];                                       \
    if (GATHER) {                                                            \
      const float* a0 = aF + aoff0 + (size_t)(KS) * 16;                      \
      const float* a1 = aF + aoff1 + (size_t)(KS) * 16;                      \
      const float* a2 = aF + aoff2 + (size_t)(KS) * 16;                      \
      const float* a3 = aF + aoff3 + (size_t)(KS) * 16;                      \
      gR0[BUF][0] = ((const float4*)a0)[0]; gR0[BUF][1] = ((const float4*)a0)[1]; \
      gR1[BUF][0] = ((const float4*)a1)[0]; gR1[BUF][1] = ((const float4*)a1)[1]; \
      gR2[BUF][0] = ((const float4*)a2)[0]; gR2[BUF][1] = ((const float4*)a2)[1]; \
      gR3[BUF][0] = ((const float4*)a3)[0]; gR3[BUF][1] = ((const float4*)a3)[1]; \
    } else {                                                                 \
      size_t o0 = aoff0 + (size_t)(KS) * 2048;                               \
      size_t o1 = aoff1 + (size_t)(KS) * 2048;                               \
      size_t o2 = aoff2 + (size_t)(KS) * 2048;                               \
      size_t o3 = aoff3 + (size_t)(KS) * 2048;                               \
      sh0[BUF] = *(const bf16x8*)(aHi + o0); sl0[BUF] = *(const bf16x8*)(aLo + o0); \
      sh1[BUF] = *(const bf16x8*)(aHi + o1); sl1[BUF] = *(const bf16x8*)(aLo + o1); \
      sh2[BUF] = *(const bf16x8*)(aHi + o2); sl2[BUF] = *(const bf16x8*)(aLo + o2); \
      sh3[BUF] = *(const bf16x8*)(aHi + o3); sl3[BUF] = *(const bf16x8*)(aLo + o3); \
    }                                                                        \
  }

#define COMPFS(BUF)                                                          \
  {                                                                          \
    bf16x8 bh, bl;                                                           \
    splitpack(bR0[BUF], bR1[BUF], bh, bl);                                   \
    bf16x8 ah, al;                                                           \
    if (GATHER) splitpack(gR0[BUF][0], gR0[BUF][1], ah, al);                 \
    else { ah = sh0[BUF]; al = sl0[BUF]; }                                   \
    acc[0] = MFMA_(ah, bh, acc[0]);                                          \
    acc[0] = MFMA_(ah, bl, acc[0]);                                          \
    acc[0] = MFMA_(al, bh, acc[0]);                                          \
    if (GATHER) splitpack(gR1[BUF][0], gR1[BUF][1], ah, al);                 \
    else { ah = sh1[BUF]; al = sl1[BUF]; }                                   \
    acc[1] = MFMA_(ah, bh, acc[1]);                                          \
    acc[1] = MFMA_(ah, bl, acc[1]);                                          \
    acc[1] = MFMA_(al, bh, acc[1]);                                          \
    if (GATHER) splitpack(gR2[BUF][0], gR2[BUF][1], ah, al);                 \
    else { ah = sh2[BUF]; al = sl2[BUF]; }                                   \
    acc[2] = MFMA_(ah, bh, acc[2]);                                          \
    acc[2] = MFMA_(ah, bl, acc[2]);                                          \
    acc[2] = MFMA_(al, bh, acc[2]);                                          \
    if (GATHER) splitpack(gR3[BUF][0], gR3[BUF][1], ah, al);                 \
    else { ah = sh3[BUF]; al = sl3[BUF]; }                                   \
    acc[3] = MFMA_(ah, bh, acc[3]);                                          \
    acc[3] = MFMA_(ah, bl, acc[3]);                                          \
    acc[3] = MFMA_(al, bh, acc[3]);                                          \
  }

  int ks = w;
  LOADFS(0, ks); ks += 8;
  int rem = nFS;
  while (rem >= 2) {
    LOADFS(1, ks); ks += 8;
    COMPFS(0);
    if (rem > 2) { LOADFS(0, ks); ks += 8; }
    COMPFS(1);
    rem -= 2;
  }
#undef LOADFS
#undef COMPFS
}

template<int EPI, int GATHER1>
__global__ __launch_bounds__(512, 2) void gemm_ks_f(
    const float* __restrict__ a1F,
    const uint16_t* __restrict__ a1Hi, const uint16_t* __restrict__ a1Lo,
    const int* __restrict__ ridx, int rstride,
    const float* __restrict__ W1, int K1,
    const uint16_t* __restrict__ a2Hi, const uint16_t* __restrict__ a2Lo,
    const float* __restrict__ W2, int K2,
    const float* __restrict__ bih, const float* __restrict__ bhh,
    float* __restrict__ cState,
    uint16_t* __restrict__ hOutHi, uint16_t* __restrict__ hOutLo,
    const float* __restrict__ bias, float* __restrict__ Cout)
{
  __shared__ float red[4][128 * 32];

  const int jb   = blockIdx.x;
  const int tid  = threadIdx.x;
  const int w    = tid >> 6;
  const int lane = tid & 63;
  const int lrow = lane & 31;
  const int lgrp = lane >> 5;

  f32x16 acc[4];
#pragma unroll
  for (int mf = 0; mf < 4; ++mf)
#pragma unroll
    for (int r = 0; r < 16; ++r) acc[mf][r] = 0.0f;

  run_phase_f<GATHER1 != 0>(acc, a1F, a1Hi, a1Lo, ridx, rstride,
                            W1, K1, EPI == 1, jb, w, lrow, lgrp);
  if (K2 > 0)
    run_phase_f<false>(acc, nullptr, a2Hi, a2Lo, nullptr, 0,
                       W2, K2, EPI == 1, jb, w, lrow, lgrp);

  const int wl = w & 3;
  if (w < 4) {
#pragma unroll
    for (int mf = 0; mf < 4; ++mf)
#pragma unroll
      for (int r = 0; r < 16; ++r) {
        const int row = mf * 32 + (r & 3) + 8 * (r >> 2) + 4 * lgrp;
        red[wl][row * 32 + (lrow ^ (row & 31))] = acc[mf][r];
      }
  }
  __syncthreads();
  if (w >= 4) {
#pragma unroll
    for (int mf = 0; mf < 4; ++mf)
#pragma unroll
      for (int r = 0; r < 16; ++r) {
        const int row = mf * 32 + (r & 3) + 8 * (r >> 2) + 4 * lgrp;
        red[wl][row * 32 + (lrow ^ (row & 31))] += acc[mf][r];
      }
  }
  __syncthreads();

  if constexpr (EPI == 1) {
    const int b  = tid & 127;
    const int uh = (tid >> 7) * 2;
#pragma unroll
    for (int q = 0; q < 2; ++q) {
      const int u = uh + q;
      float gs[4];
#pragma unroll
      for (int g = 0; g < 4; ++g) {
        const int cs = (g * 8 + u) ^ (b & 31);
        gs[g] = ((red[0][b * 32 + cs] + red[1][b * 32 + cs])
                 + red[2][b * 32 + cs]) + red[3][b * 32 + cs];
      }
      const int n = jb * 8 + u;
      float gi = gs[0] + bih[n]          + bhh[n];
      float gf = gs[1] + bih[H_ + n]     + bhh[H_ + n];
      float gg = gs[2] + bih[2 * H_ + n] + bhh[2 * H_ + n];
      float go = gs[3] + bih[3 * H_ + n] + bhh[3 * H_ + n];
      float si = 1.f / (1.f + expf(-gi));
      float sf = 1.f / (1.f + expf(-gf));
      float so = 1.f / (1.f + expf(-go));
      const size_t ci = (size_t)b * H_ + n;
      float cv = sf * cState[ci] + si * tanhf(gg);
      cState[ci] = cv;
      float hv = so * tanhf(cv);
      uint16_t hh, hl;
      split2(hv, hh, hl);
      const size_t hoff = (size_t)((n >> 4) * 4 + (b >> 5)) * 512
                        + (size_t)((n >> 3) & 1) * 256
                        + (size_t)(b & 31) * 8 + (size_t)(n & 7);
      hOutHi[hoff] = hh;
      hOutLo[hoff] = hl;
    }
  } else {
    const int b  = tid & 127;
    const int ch = (tid >> 7) * 8;
#pragma unroll
    for (int q = 0; q < 8; ++q) {
      const int col = ch + q;
      const int cs  = col ^ (b & 31);
      float v = ((red[0][b * 32 + cs] + red[1][b * 32 + cs])
                 + red[2][b * 32 + cs]) + red[3][b * 32 + cs];
      Cout[(size_t)b * V_ + jb * 32 + col] = v + bias[jb * 32 + col];
    }
  }
}

// ---------------------------------------------------------------------------
// categorical sampling (verbatim from passing rounds 3-7,10)
// ---------------------------------------------------------------------------
__global__ __launch_bounds__(256) void sample_kernel(
    const float* __restrict__ logits, const uint32_t* __restrict__ keys,
    int t, int* __restrict__ out, int col)
{
  const int b = blockIdx.x;
  const int tid = threadIdx.x;
  const uint32_t k0 = keys[2 * t];
  const uint32_t k1 = keys[2 * t + 1];
  const float* lrow = logits + (size_t)b * V_;

  float best = -3.4e38f;
  int bestIdx = 0;
  for (int v = tid; v < V_; v += 256) {
    uint32_t j = (uint32_t)(b * V_ + v);
    uint32_t o0, o1;
    threefry2x32(k0, k1, 0u, j, o0, o1);
    uint32_t bits = o0 ^ o1;
    float f = __uint_as_float((bits >> 9) | 0x3f800000u) - 1.0f;
    float u = fmaxf(1.17549435e-38f, f + 1.17549435e-38f);
    float t1 = (float)log((double)u);
    float t2 = -t1;
    float t3 = (float)log((double)t2);
    float val = (-t3) + lrow[v];
    if (val > best) { best = val; bestIdx = v; }
  }

  __shared__ float sv[256];
  __shared__ int   si[256];
  sv[tid] = best; si[tid] = bestIdx;
  __syncthreads();
  for (int s = 128; s > 0; s >>= 1) {
    if (tid < s) {
      float v2 = sv[tid + s]; int i2 = si[tid + s];
      if (v2 > sv[tid] || (v2 == sv[tid] && i2 < si[tid])) { sv[tid] = v2; si[tid] = i2; }
    }
    __syncthreads();
  }
  if (tid == 0) out[b * S_ + col] = si[0];
}

// ---------------------------------------------------------------------------
extern "C" void kernel_launch(void* const* d_in, const int* in_sizes, int n_in,
                              void* d_out, int out_size, void* d_ws, size_t ws_size,
                              hipStream_t stream) {
  const int*   x    = (const int*)  d_in[0];
  const float* emb  = (const float*)d_in[3];
  const float* Wih0 = (const float*)d_in[4];
  const float* Whh0 = (const float*)d_in[5];
  const float* bih0 = (const float*)d_in[6];
  const float* bhh0 = (const float*)d_in[7];
  const float* Wih1 = (const float*)d_in[8];
  const float* Whh1 = (const float*)d_in[9];
  const float* bih1 = (const float*)d_in[10];
  const float* bhh1 = (const float*)d_in[11];
  const float* Wlin = (const float*)d_in[12];
  const float* blin = (const float*)d_in[13];
  int* out = (int*)d_out;

  // ---- workspace carve-up ----
  char* wp = (char*)d_ws;
  size_t o = 0;
  auto alloc = [&](size_t bytes) {
    void* p = wp + o; o += (bytes + 255) & ~(size_t)255; return p;
  };
  uint32_t* keys   = (uint32_t*)alloc(512);
  float*    logits = (float*)   alloc((size_t)B_ * V_ * 4);
  float*    c0     = (float*)   alloc((size_t)B_ * H_ * 4);   // zero-block start
  float*    c1     = (float*)   alloc((size_t)B_ * H_ * 4);
  uint16_t* hS0hi[2]; uint16_t* hS0lo[2]; uint16_t* hS1hi[2]; uint16_t* hS1lo[2];
  for (int i = 0; i < 2; ++i) hS0hi[i] = (uint16_t*)alloc((size_t)B_ * H_ * 2);
  for (int i = 0; i < 2; ++i) hS0lo[i] = (uint16_t*)alloc((size_t)B_ * H_ * 2);
  for (int i = 0; i < 2; ++i) hS1hi[i] = (uint16_t*)alloc((size_t)B_ * H_ * 2);
  for (int i = 0; i < 2; ++i) hS1lo[i] = (uint16_t*)alloc((size_t)B_ * H_ * 2);
  size_t zeroBytes = (size_t)((char*)hS1lo[1] + (size_t)B_ * H_ * 2 - (char*)c0);

  // panel allocations (only valid if ws_size allows)
  const size_t nIh0 = (size_t)H4_ * E_;    // 4.19M elems
  const size_t nHh  = (size_t)H4_ * H_;    // 16.78M (x3)
  const size_t nLin = (size_t)V_ * H_;     // 16.38M
  uint16_t* PHih0 = (uint16_t*)alloc(nIh0 * 2);
  uint8_t*  PMih0 = (uint8_t*) alloc(nIh0);
  uint16_t* PHhh0 = (uint16_t*)alloc(nHh * 2);
  uint8_t*  PMhh0 = (uint8_t*) alloc(nHh);
  uint16_t* PHih1 = (uint16_t*)alloc(nHh * 2);
  uint8_t*  PMih1 = (uint8_t*) alloc(nHh);
  uint16_t* PHhh1 = (uint16_t*)alloc(nHh * 2);
  uint8_t*  PMhh1 = (uint8_t*) alloc(nHh);
  uint16_t* PHlin = (uint16_t*)alloc(nLin * 2);
  uint8_t*  PMlin = (uint8_t*) alloc(nLin);
  const bool usePacked = (o <= ws_size);

  hipMemsetAsync(c0, 0, zeroBytes, stream);
  keys_kernel<<<1, 64, 0, stream>>>(keys);
  copy_prefix<<<(B_ * GIVEN_) / 256, 256, 0, stream>>>(x, out);

  if (usePacked) {
    // panel packing: grid = jb_count * nks, 64 threads (one wave per frag)
    pack3_panel<<<256 * 32,  64, 0, stream>>>(Wih0, PHih0, PMih0, E_, 32, 1);
    pack3_panel<<<256 * 128, 64, 0, stream>>>(Whh0, PHhh0, PMhh0, H_, 128, 1);
    pack3_panel<<<256 * 128, 64, 0, stream>>>(Wih1, PHih1, PMih1, H_, 128, 1);
    pack3_panel<<<256 * 128, 64, 0, stream>>>(Whh1, PHhh1, PMhh1, H_, 128, 1);
    pack3_panel<<<250 * 128, 64, 0, stream>>>(Wlin, PHlin, PMlin, H_, 128, 0);
  }

  int p = 0;
  auto lstm_step = [&](const int* ridx) {
    if (usePacked) {
      gemm_ks_p<1, 1><<<H_ / 8, 512, 0, stream>>>(
          emb, nullptr, nullptr, ridx, S_, PHih0, PMih0, E_,
          hS0hi[p], hS0lo[p], PHhh0, PMhh0, H_,
          bih0, bhh0, c0, hS0hi[p ^ 1], hS0lo[p ^ 1], nullptr, nullptr);
      gemm_ks_p<1, 0><<<H_ / 8, 512, 0, stream>>>(
          nullptr, hS0hi[p ^ 1], hS0lo[p ^ 1], nullptr, 0, PHih1, PMih1, H_,
          hS1hi[p], hS1lo[p], PHhh1, PMhh1, H_,
          bih1, bhh1, c1, hS1hi[p ^ 1], hS1lo[p ^ 1], nullptr, nullptr);
    } else {
      gemm_ks_f<1, 1><<<H_ / 8, 512, 0, stream>>>(
          emb, nullptr, nullptr, ridx, S_, Wih0, E_,
          hS0hi[p], hS0lo[p], Whh0, H_,
          bih0, bhh0, c0, hS0hi[p ^ 1], hS0lo[p ^ 1], nullptr, nullptr);
      gemm_ks_f<1, 0><<<H_ / 8, 512, 0, stream>>>(
          nullptr, hS0hi[p ^ 1], hS0lo[p ^ 1], nullptr, 0, Wih1, H_,
          hS1hi[p], hS1lo[p], Whh1, H_,
          bih1, bhh1, c1, hS1hi[p ^ 1], hS1lo[p ^ 1], nullptr, nullptr);
    }
    p ^= 1;
  };

  // teacher forcing
  for (int t = 0; t < GIVEN_; ++t) {
    lstm_step(x + t);
  }

  // rollout
  for (int t = 0; t < S_ - GIVEN_; ++t) {
    const int* ridx = (t == 0) ? (x + (GIVEN_ - 1)) : (out + (GIVEN_ + t - 1));
    lstm_step(ridx);
    if (usePacked) {
      gemm_ks_p<0, 0><<<V_ / 32, 512, 0, stream>>>(
          nullptr, hS1hi[p], hS1lo[p], nullptr, 0, PHlin, PMlin, H_,
          nullptr, nullptr, nullptr, nullptr, 0,
          nullptr, nullptr, nullptr, nullptr, nullptr, blin, logits);
    } else {
      gemm_ks_f<0, 0><<<V_ / 32, 512, 0, stream>>>(
          nullptr, hS1hi[p], hS1lo[p], nullptr, 0, Wlin, H_,
          nullptr, nullptr, nullptr, 0,
          nullptr, nullptr, nullptr, nullptr, nullptr, blin, logits);
    }
    sample_kernel<<<B_, 256, 0, stream>>>(logits, keys, t, out, GIVEN_ + t);
  }
}